// Round 1
// 318.441 us; speedup vs baseline: 1.0673x; 1.0673x over previous
//
#include <hip/hip_runtime.h>
#include <hip/hip_bf16.h>

#define N_NODES 50000
#define N_EDGES 800000
#define F_INS   128
#define HIDDEN  16
#define HEADS   8
#define HO      128      // HEADS*HIDDEN
#define C_OUT   16
#define NEG_SLOPE 0.2f
#define SLOT    64       // fixed col slots per node; P(Poisson(16) > 64) ~ 1e-20
#define NB_G1   ((N_NODES + 63) / 64)     // 782 blocks for MFMA gemm1 (per graph)
#define NB_GAT1 ((N_NODES + 3) / 4)       // 12500 blocks for gat1 (per graph)
#define NB_G2   ((N_NODES + 16) / 16)     // 3126 blocks for gemm2 (per graph, covers dummy row)

// padded row counts / strides (dummy node index == N_NODES)
#define NP      50016                      // N_NODES rounded up (+dummy row), 16-aligned
#define AS_ST   ((size_t)NP * 8)           // floats per graph for as1/ad1
#define H1B_ST  ((size_t)NP * 64)          // u32 per graph for h1b (bf16 pairs)
#define HL1_ST  ((size_t)N_NODES * 64)     // u32 per graph for hL1
#define H2_ST   ((size_t)NP * 16)          // floats per graph for h2
#define AS2_ST  ((size_t)NP)               // floats per graph for as2/ad2

// ---- two-phase CSR build constants ----
#define NCLS     128                       // node classes; cls = (d*1342)>>19, <=391 nodes/class
#define CLS_MUL  1342u
#define CLS_SH   19
#define CAP      8192                      // bucket capacity per (graph,class); expect ~6256
#define CHUNK    2048                      // edges per k_bucket block (256 thr x 8)
#define NB_BKT   ((N_EDGES + CHUNK - 1) / CHUNK)   // 391 chunks per graph

typedef unsigned short u16;
typedef unsigned int   u32;
typedef int v4i __attribute__((ext_vector_type(4)));
typedef short bf16x8 __attribute__((ext_vector_type(8)));
typedef float f32x4 __attribute__((ext_vector_type(4)));

__device__ __forceinline__ float bf2f(u16 u) {
    union { u32 i; float f; } t; t.i = ((u32)u) << 16; return t.f;
}
__device__ __forceinline__ float bflo(u32 q) {
    union { u32 i; float f; } t; t.i = q << 16; return t.f;
}
__device__ __forceinline__ float bfhi(u32 q) {
    union { u32 i; float f; } t; t.i = q & 0xFFFF0000u; return t.f;
}
__device__ __forceinline__ u32 f2bf(float f) {
    union { float f; u32 i; } t; t.f = f;
    u32 x = t.i;
    u32 lsb = (x >> 16) & 1u;
    x += 0x7FFFu + lsb;
    return x >> 16;
}
__device__ __forceinline__ float lrelu(float t) {
    return fmaxf(t, NEG_SLOPE * t);   // exact leaky-relu: 0.2t>t iff t<0
}
__device__ __forceinline__ int cls_of(int d) { return (int)(((u32)d * CLS_MUL) >> CLS_SH); }
__host__ __device__ __forceinline__ int cls_base(int c) { return (int)(((u32)c * 524288u + (CLS_MUL - 1)) / CLS_MUL); }

// ---------------- prep: W1T bf16 [c][k] + A1T bf16 [n][k] (n=2h+{s,d}) ----------------
__global__ void k_wt(const float* __restrict__ W1, const float* __restrict__ a1s,
                     const float* __restrict__ a1d, u32* __restrict__ w1t,
                     u32* __restrict__ a1t) {
    int t = threadIdx.x;
    if (blockIdx.x < 32) {
        int e = blockIdx.x * 256 + t;    // 0..8191
        int c = e >> 6, kp = e & 63;
        float lo = W1[(2 * kp) * 128 + c];
        float hi = W1[(2 * kp + 1) * 128 + c];
        w1t[e] = (f2bf(hi) << 16) | f2bf(lo);
    } else {
        #pragma unroll
        for (int i = 0; i < 4; ++i) {
            int wi = t + i * 256;        // 0..1023
            int n = wi >> 6, kp = wi & 63;
            int h = n >> 1;
            const float* av = ((n & 1) ? a1d : a1s) + h * 16;
            float s0 = 0.f, s1 = 0.f;
            #pragma unroll
            for (int c = 0; c < 16; ++c) {
                s0 += W1[(2 * kp) * 128 + h * 16 + c] * av[c];
                s1 += W1[(2 * kp + 1) * 128 + h * 16 + c] * av[c];
            }
            a1t[wi] = (f2bf(s1) << 16) | f2bf(s0);
        }
    }
}

// ---------------- phase A: bucket edges by node-class (few global atomics) ----------------
__launch_bounds__(256)
__global__ void k_bucket(const int* __restrict__ ei0, const int* __restrict__ ei1,
                         int* __restrict__ gcur, u32* __restrict__ bucket) {
    __shared__ int cnt[NCLS];
    __shared__ int base[NCLS];
    int t = threadIdx.x;
    int g = blockIdx.x & 1;
    int chunk = blockIdx.x >> 1;
    int e0 = chunk * CHUNK + t * 8;
    bool act = e0 < N_EDGES;

    if (t < NCLS) cnt[t] = 0;
    __syncthreads();

    const int* src = g ? ei1 : ei0;
    const int* dst = src + N_EDGES;
    int d8[8], s8[8], c8[8];
    if (act) {
        v4i da = *(const v4i*)(dst + e0), db = *(const v4i*)(dst + e0 + 4);
        v4i sa = *(const v4i*)(src + e0), sb = *(const v4i*)(src + e0 + 4);
        d8[0]=da[0]; d8[1]=da[1]; d8[2]=da[2]; d8[3]=da[3];
        d8[4]=db[0]; d8[5]=db[1]; d8[6]=db[2]; d8[7]=db[3];
        s8[0]=sa[0]; s8[1]=sa[1]; s8[2]=sa[2]; s8[3]=sa[3];
        s8[4]=sb[0]; s8[5]=sb[1]; s8[6]=sb[2]; s8[7]=sb[3];
        #pragma unroll
        for (int j = 0; j < 8; ++j) {
            c8[j] = cls_of(d8[j]);
            atomicAdd(&cnt[c8[j]], 1);
        }
    }
    __syncthreads();
    if (t < NCLS) {
        int n = cnt[t];
        base[t] = n ? atomicAdd(&gcur[g * NCLS + t], n) : 0;
        cnt[t] = 0;
    }
    __syncthreads();
    if (act) {
        #pragma unroll
        for (int j = 0; j < 8; ++j) {
            int c = c8[j];
            int p = atomicAdd(&cnt[c], 1);
            bucket[(size_t)(g * NCLS + c) * CAP + base[c] + p] =
                ((u32)d8[j] << 16) | (u32)s8[j];
        }
    }
}

// ---------------- phase B: per-(graph,class) CSR build + pad-to-8 with dummy node ----------------
__launch_bounds__(256)
__global__ void k_build(const int* __restrict__ gcur, const u32* __restrict__ bucket,
                        int* __restrict__ cursor, u16* __restrict__ col) {
    __shared__ int cnt[391];
    int t = threadIdx.x;
    int c = blockIdx.x & (NCLS - 1);
    int g = blockIdx.x >> 7;
    int d0 = cls_base(c);
    int d1 = (c == NCLS - 1) ? N_NODES : cls_base(c + 1);
    int nn = d1 - d0;
    for (int j = t; j < nn; j += 256) cnt[j] = 0;
    __syncthreads();

    int size = gcur[g * NCLS + c];
    const u32* bp = bucket + (size_t)(g * NCLS + c) * CAP;
    u16* cl = col + (size_t)g * N_NODES * SLOT;
    for (int i = t; i < size; i += 256) {
        u32 e = bp[i];
        int d = (int)(e >> 16);
        int s = (int)(e & 0xFFFFu);
        int p = atomicAdd(&cnt[d - d0], 1);
        if (p < SLOT) cl[(size_t)d * SLOT + p] = (u16)s;
    }
    __syncthreads();
    int* cur = cursor + g * N_NODES;
    for (int j = t; j < nn; j += 256) {
        int d = d0 + j;
        int raw = cnt[j];
        int n0 = min(raw, SLOT);
        int n1 = (n0 + 7) & ~7;            // pad to next multiple of 8 with dummy node
        u16* cw = cl + (size_t)d * SLOT;
        for (int p = n0; p < n1; ++p) cw[p] = (u16)N_NODES;
        cur[d] = raw;
    }
}

// ---------------- GEMM1 via MFMA, both graphs, writes dummy row N_NODES ----------------
__launch_bounds__(256)
__global__ void k_gemm1(const float* __restrict__ x1g, const float* __restrict__ x2g,
                        const u32* __restrict__ w1t, const u32* __restrict__ a1t,
                        u32* __restrict__ h1b, float* __restrict__ as_,
                        float* __restrict__ ad_) {
    __shared__ u32 xls[4096];   // 16 KB: [wid][kt][lane][jj]
    int t = threadIdx.x;
    int bid = blockIdx.x;
    int g = bid >= NB_G1;
    if (g) bid -= NB_G1;
    const float* x = g ? x2g : x1g;
    u32*   h1o = h1b + (size_t)g * H1B_ST;
    float* aso = as_ + (size_t)g * AS_ST;
    float* ado = ad_ + (size_t)g * AS_ST;
    int r0 = bid * 64;

    const float2* x2p = (const float2*)x;
    #pragma unroll
    for (int i = 0; i < 16; ++i) {
        int A = t + i * 256;
        int wi = A >> 10, kt = (A >> 8) & 3, L = (A >> 2) & 63, jj = A & 3;
        int m = L & 15, qd = L >> 4;
        int r = r0 + wi * 16 + m;
        int pp = kt * 16 + qd * 4 + jj;
        float2 v = make_float2(0.f, 0.f);
        if (r < N_NODES) v = x2p[(size_t)r * 64 + pp];
        xls[A] = (f2bf(v.y) << 16) | f2bf(v.x);
    }
    __syncthreads();

    int lane = t & 63;
    int wid = t >> 6;
    int n = lane & 15, quad = lane >> 4;

    f32x4 acc[8], acca;
    #pragma unroll
    for (int ct = 0; ct < 8; ++ct) acc[ct] = (f32x4){0.f, 0.f, 0.f, 0.f};
    acca = (f32x4){0.f, 0.f, 0.f, 0.f};

    #pragma unroll
    for (int kt = 0; kt < 4; ++kt) {
        union { uint4 u; bf16x8 v; } af;
        af.u = *(const uint4*)(xls + wid * 1024 + kt * 256 + lane * 4);
        #pragma unroll
        for (int ct = 0; ct < 8; ++ct) {
            union { uint4 u; bf16x8 v; } bf_;
            bf_.u = *(const uint4*)(w1t + (ct * 16 + n) * 64 + kt * 16 + quad * 4);
            acc[ct] = __builtin_amdgcn_mfma_f32_16x16x32_bf16(af.v, bf_.v, acc[ct], 0, 0, 0);
        }
        union { uint4 u; bf16x8 v; } ba;
        ba.u = *(const uint4*)(a1t + n * 64 + kt * 16 + quad * 4);
        acca = __builtin_amdgcn_mfma_f32_16x16x32_bf16(af.v, ba.v, acca, 0, 0, 0);
    }

    // C/D layout: col = lane&15, row = quad*4+reg [m89]
    int h = n >> 1;
    #pragma unroll
    for (int reg = 0; reg < 4; ++reg) {
        int gr = r0 + wid * 16 + quad * 4 + reg;
        bool ok = gr <= N_NODES;           // include dummy row
        float av = (gr == N_NODES) ? -1e30f : acca[reg];  // dummy: w=exp(leaky(-1e30+ad))=0
        if (ok) {
            if (n & 1) ado[gr * 8 + h] = av;
            else       aso[gr * 8 + h] = av;
        }
        #pragma unroll
        for (int ct = 0; ct < 8; ++ct) {
            u32 my = f2bf(acc[ct][reg]);
            u32 ot = (u32)__shfl_xor((int)my, 1);
            if (!(n & 1) && ok)
                h1o[(size_t)gr * 64 + ct * 8 + (n >> 1)] = (ot << 16) | my;  // dummy row = 0
        }
    }
}

// ---------------- GAT layer 1 gather: one wave per node, both graphs ----------------
// Alpha-lane transpose: lane L computes exp-weight for edge (L>>3), head (L&7) of the
// 8-edge batch (1 exp/batch instead of 8), then redistributes via ds_bpermute
// (source lane j*8+hc) on the otherwise-idle LDS pipe. CSR padded to x8 -> no tails.
__launch_bounds__(256)
__global__ void k_gat1(const u32* __restrict__ h1b, const float* __restrict__ as_,
                       const float* __restrict__ ad_, const int* __restrict__ cursor,
                       const u16* __restrict__ col, const float* __restrict__ b1,
                       u32* __restrict__ hL1) {
    int t = threadIdx.x;
    int lane = t & 63;
    int bid = blockIdx.x;
    int g = bid >= NB_GAT1;
    if (g) bid -= NB_GAT1;
    int node = bid * 4 + (t >> 6);         // grid exact: 12500*4 == N_NODES

    const u32*   h1  = h1b + (size_t)g * H1B_ST;
    const float* as1 = as_ + (size_t)g * AS_ST;
    const float* ad1 = ad_ + (size_t)g * AS_ST;
    const u16*   cp  = col + ((size_t)g * N_NODES + node) * SLOT;

    int hc = lane >> 3;                    // channel head (lane covers ch 2L,2L+1)
    int ha = lane & 7;                     // alpha-duty head
    int j8 = lane >> 3;                    // alpha-duty edge-in-batch
    int vb = hc << 2;                      // bpermute byte base: src lane j*8+hc

    float ad_a = ad1[node * 8 + ha];
    float as_c = as1[node * 8 + hc];
    float ad_c = ad1[node * 8 + hc];

    // self loop
    float w = __expf(lrelu(as_c + ad_c));
    float denom = w;
    u32 q = h1[(u32)node * 64 + (u32)lane];
    float ax = w * bflo(q), ay = w * bfhi(q);

    int deg = min(cursor[g * N_NODES + node], SLOT);
    int nb = (deg + 7) >> 3;               // padded CSR: exactly nb full batches
    for (int b = 0; b < nb; ++b) {
        int e = b * 8;
        ushort4 sa4 = *(const ushort4*)(cp + e);
        ushort4 sb4 = *(const ushort4*)(cp + e + 4);
        u32 q0 = h1[((u32)sa4.x << 6) | (u32)lane];
        u32 q1 = h1[((u32)sa4.y << 6) | (u32)lane];
        u32 q2 = h1[((u32)sa4.z << 6) | (u32)lane];
        u32 q3 = h1[((u32)sa4.w << 6) | (u32)lane];
        u32 q4 = h1[((u32)sb4.x << 6) | (u32)lane];
        u32 q5 = h1[((u32)sb4.y << 6) | (u32)lane];
        u32 q6 = h1[((u32)sb4.z << 6) | (u32)lane];
        u32 q7 = h1[((u32)sb4.w << 6) | (u32)lane];

        int sA = cp[e + j8];               // this lane's alpha-duty source
        float A = as1[sA * 8 + ha];        // dummy node: A=-1e30 -> w=0
        int wli = __float_as_int(__expf(lrelu(A + ad_a)));
        float w0 = __int_as_float(__builtin_amdgcn_ds_bpermute(vb,       wli));
        float w1 = __int_as_float(__builtin_amdgcn_ds_bpermute(vb + 32,  wli));
        float w2 = __int_as_float(__builtin_amdgcn_ds_bpermute(vb + 64,  wli));
        float w3 = __int_as_float(__builtin_amdgcn_ds_bpermute(vb + 96,  wli));
        float w4 = __int_as_float(__builtin_amdgcn_ds_bpermute(vb + 128, wli));
        float w5 = __int_as_float(__builtin_amdgcn_ds_bpermute(vb + 160, wli));
        float w6 = __int_as_float(__builtin_amdgcn_ds_bpermute(vb + 192, wli));
        float w7 = __int_as_float(__builtin_amdgcn_ds_bpermute(vb + 224, wli));

        denom += ((w0 + w1) + (w2 + w3)) + ((w4 + w5) + (w6 + w7));
        ax += w0 * bflo(q0) + w1 * bflo(q1) + w2 * bflo(q2) + w3 * bflo(q3)
            + w4 * bflo(q4) + w5 * bflo(q5) + w6 * bflo(q6) + w7 * bflo(q7);
        ay += w0 * bfhi(q0) + w1 * bfhi(q1) + w2 * bfhi(q2) + w3 * bfhi(q3)
            + w4 * bfhi(q4) + w5 * bfhi(q5) + w6 * bfhi(q6) + w7 * bfhi(q7);
    }
    float inv = 1.f / (denom + 1e-16f);
    int c = lane * 2;
    float o0 = ax * inv + b1[c];
    float o1 = ay * inv + b1[c + 1];
    o0 = (o0 > 0.f) ? o0 : (__expf(o0) - 1.f);   // ELU
    o1 = (o1 > 0.f) ? o1 : (__expf(o1) - 1.f);
    hL1[(size_t)g * HL1_ST + (size_t)node * 64 + lane] = (f2bf(o1) << 16) | f2bf(o0);
}

// ---------------- GEMM2 (+fused alpha2), both graphs, writes dummy row ----------------
__launch_bounds__(256)
__global__ void k_gemm2(const u32* __restrict__ hL1, const float* __restrict__ W2,
                        const float* __restrict__ a2s, const float* __restrict__ a2d,
                        float* __restrict__ h2, float* __restrict__ as2,
                        float* __restrict__ ad2) {
    __shared__ float w2s[F_INS * C_OUT];  // 8 KB, [k][c]
    __shared__ float hs[16 * 136];        // padded stride 136
    int t = threadIdx.x;
    int bid = blockIdx.x;
    int g = bid >= NB_G2;
    if (g) bid -= NB_G2;
    const u16* hL = (const u16*)(hL1 + (size_t)g * HL1_ST);
    float* h2o  = h2  + (size_t)g * H2_ST;
    float* as2o = as2 + (size_t)g * AS2_ST;
    float* ad2o = ad2 + (size_t)g * AS2_ST;

    const float4* w4 = (const float4*)W2;     // 512 float4s
    #pragma unroll
    for (int i = 0; i < 2; ++i) {
        int idx = t + i * 256;
        ((float4*)w2s)[idx] = w4[idx];
    }
    int r0 = bid * 16;
    const ushort4* hg = (const ushort4*)hL;   // 32 ushort4 per row
    #pragma unroll
    for (int i = 0; i < 2; ++i) {
        int idx = t + i * 256;      // 0..511
        int r  = idx >> 5;          // 0..15
        int c4 = idx & 31;
        ushort4 qq = make_ushort4(0, 0, 0, 0);
        if (r0 + r < N_NODES) qq = hg[(size_t)(r0 + r) * 32 + c4];
        float4 v; v.x = bf2f(qq.x); v.y = bf2f(qq.y); v.z = bf2f(qq.z); v.w = bf2f(qq.w);
        *(float4*)(hs + r * 136 + c4 * 4) = v;
    }
    __syncthreads();

    int c = t & 15, r = t >> 4;
    float acc = 0.f;
    #pragma unroll 8
    for (int k = 0; k < F_INS; ++k) acc += hs[r * 136 + k] * w2s[k * C_OUT + c];
    int n = r0 + r;
    if (n <= N_NODES) h2o[(size_t)n * C_OUT + c] = acc;   // dummy row: acc==0

    // fused alpha2: 16-lane butterfly within each row group
    float sa = acc * a2s[c];
    float sd = acc * a2d[c];
    #pragma unroll
    for (int m = 1; m < 16; m <<= 1) {
        sa += __shfl_xor(sa, m);
        sd += __shfl_xor(sd, m);
    }
    if (c == 0 && n <= N_NODES) {
        as2o[n] = (n == N_NODES) ? -1e30f : sa;           // dummy: w=0
        ad2o[n] = sd;
    }
}

// ---------------- layer-2 per-node gather (padded CSR, no tails) ----------------
__device__ __forceinline__ float gat2_node(const float* __restrict__ h2g,
                                           const float* __restrict__ as2g,
                                           const float* __restrict__ ad2g,
                                           const int* __restrict__ curg,
                                           const u16* __restrict__ cp,
                                           const float* __restrict__ b2,
                                           int node, int c) {
    float ad = ad2g[node];
    float w = __expf(lrelu(as2g[node] + ad));
    float denom = w;
    float acc = w * h2g[(u32)node * C_OUT + (u32)c];

    int deg = min(curg[node], SLOT);
    int nb = (deg + 7) >> 3;
    for (int b = 0; b < nb; ++b) {
        const u16* ce = cp + b * 8;
        ushort4 sa4 = *(const ushort4*)ce;
        ushort4 sb4 = *(const ushort4*)(ce + 4);
        int s0 = sa4.x, s1 = sa4.y, s2 = sa4.z, s3 = sa4.w;
        int s4 = sb4.x, s5 = sb4.y, s6 = sb4.z, s7 = sb4.w;
        float A0 = as2g[s0], A1 = as2g[s1], A2 = as2g[s2], A3 = as2g[s3];
        float A4 = as2g[s4], A5 = as2g[s5], A6 = as2g[s6], A7 = as2g[s7];
        float v0 = h2g[(u32)(s0 * C_OUT + c)], v1 = h2g[(u32)(s1 * C_OUT + c)];
        float v2 = h2g[(u32)(s2 * C_OUT + c)], v3 = h2g[(u32)(s3 * C_OUT + c)];
        float v4 = h2g[(u32)(s4 * C_OUT + c)], v5 = h2g[(u32)(s5 * C_OUT + c)];
        float v6 = h2g[(u32)(s6 * C_OUT + c)], v7 = h2g[(u32)(s7 * C_OUT + c)];
        float w0 = __expf(lrelu(A0 + ad)), w1 = __expf(lrelu(A1 + ad));
        float w2 = __expf(lrelu(A2 + ad)), w3 = __expf(lrelu(A3 + ad));
        float w4 = __expf(lrelu(A4 + ad)), w5 = __expf(lrelu(A5 + ad));
        float w6 = __expf(lrelu(A6 + ad)), w7 = __expf(lrelu(A7 + ad));
        denom += ((w0 + w1) + (w2 + w3)) + ((w4 + w5) + (w6 + w7));
        acc += (w0 * v0 + w1 * v1 + w2 * v2 + w3 * v3)
             + (w4 * v4 + w5 * v5 + w6 * v6 + w7 * v7);
    }
    return acc / (denom + 1e-16f) + b2[c];
}

// ---------------- GAT layer 2 both graphs + fused epilogue ----------------
__launch_bounds__(256)
__global__ void k_gat2e(const float* __restrict__ h2, const float* __restrict__ as2,
                        const float* __restrict__ ad2, const int* __restrict__ cursor,
                        const u16* __restrict__ col, const float* __restrict__ b2,
                        float* __restrict__ out) {
    int t = threadIdx.x;
    int node = blockIdx.x * 16 + (t >> 4);   // grid exact: 3125*16 == N_NODES
    int c = t & 15;

    float yv = gat2_node(h2, as2, ad2, cursor,
                         col + (size_t)node * SLOT, b2, node, c);
    float zv = gat2_node(h2 + H2_ST, as2 + AS2_ST, ad2 + AS2_ST, cursor + N_NODES,
                         col + ((size_t)N_NODES + node) * SLOT, b2, node, c);

    float my = yv, mz = zv;
    #pragma unroll
    for (int m = 1; m < 16; m <<= 1) {
        my = fmaxf(my, __shfl_xor(my, m));
        mz = fmaxf(mz, __shfl_xor(mz, m));
    }
    float sy = __expf(yv - my), sz = __expf(zv - mz);
    float dot = yv * zv, ny = yv * yv, nz = zv * zv;
    #pragma unroll
    for (int m = 1; m < 16; m <<= 1) {
        sy  += __shfl_xor(sy, m);
        sz  += __shfl_xor(sz, m);
        dot += __shfl_xor(dot, m);
        ny  += __shfl_xor(ny, m);
        nz  += __shfl_xor(nz, m);
    }
    float lsey = my + __logf(sy);
    float lsez = mz + __logf(sz);
    float omc = 1.f - dot / (fmaxf(sqrtf(ny), 1e-8f) * fmaxf(sqrtf(nz), 1e-8f));

    const int O1 = N_NODES * C_OUT;            //  800000: 1-cos
    const int O2 = O1 + N_NODES;               //  850000: ls_z
    const int O3 = O2 + N_NODES * C_OUT;       // 1650000: ls_y
    const int O4 = O3 + N_NODES * C_OUT;       // 2450000: ls_y
    float ly = yv - lsey;
    float lz = zv - lsez;
    int base = node * 16 + c;
    out[base]      = ly;
    out[O2 + base] = lz;
    out[O3 + base] = ly;
    out[O4 + base] = ly;
    if (c == 0) out[O1 + node] = omc;
}

extern "C" void kernel_launch(void* const* d_in, const int* in_sizes, int n_in,
                              void* d_out, int out_size, void* d_ws, size_t ws_size,
                              hipStream_t stream) {
    (void)in_sizes; (void)n_in; (void)out_size; (void)ws_size;
    const float* x1  = (const float*)d_in[0];
    const int*   ei1 = (const int*)d_in[1];
    const float* x2  = (const float*)d_in[2];
    const int*   ei2 = (const int*)d_in[3];
    const float* W1  = (const float*)d_in[4];
    const float* a1s = (const float*)d_in[5];
    const float* a1d = (const float*)d_in[6];
    const float* b1  = (const float*)d_in[7];
    const float* W2  = (const float*)d_in[8];
    const float* a2s = (const float*)d_in[9];
    const float* a2d = (const float*)d_in[10];
    const float* b2  = (const float*)d_in[11];
    float* out = (float*)d_out;

    // Workspace layout: ~78 MB. bucket (8 MB) aliases h1b (25.6 MB):
    // consumed by k_build before k_gemm1 first writes h1b.
    char* p = (char*)d_ws;
    int* gcur      = (int*)p; p += (size_t)2 * NCLS * 4;             //   1 KB
    u32* w1t       = (u32*)p; p += (size_t)128 * 64 * 4;             //  32 KB (bf16 W1T [c][k])
    u32* a1t       = (u32*)p; p += (size_t)16 * 64 * 4;              //   4 KB (bf16 A1T [n][k])
    int* cursor    = (int*)p; p += (size_t)2 * N_NODES * 4;          //   0.4 MB
    u16* col       = (u16*)p; p += (size_t)2 * N_NODES * SLOT * 2;   //  12.8 MB
    float* as1  = (float*)p; p += (size_t)2 * AS_ST * 4;             //   3.2 MB
    float* ad1  = (float*)p; p += (size_t)2 * AS_ST * 4;             //   3.2 MB
    float* h2   = (float*)p; p += (size_t)2 * H2_ST * 4;             //   6.4 MB
    float* as2  = (float*)p; p += (size_t)2 * AS2_ST * 4;            //   0.4 MB
    float* ad2  = (float*)p; p += (size_t)2 * AS2_ST * 4;            //   0.4 MB
    u32* hL1    = (u32*)p;   p += (size_t)2 * HL1_ST * 4;            //  25.6 MB (bf16)
    u32* h1b    = (u32*)p;   p += (size_t)2 * H1B_ST * 4;            //  25.6 MB (bf16)
    u32* bucket = h1b;                                               //   8 MB alias

    hipMemsetAsync(gcur, 0, (size_t)2 * NCLS * 4, stream);
    k_wt    <<<33, 256, 0, stream>>>(W1, a1s, a1d, w1t, a1t);
    k_bucket<<<2 * NB_BKT, 256, 0, stream>>>(ei1, ei2, gcur, bucket);
    k_build <<<2 * NCLS, 256, 0, stream>>>(gcur, bucket, cursor, col);
    k_gemm1 <<<2 * NB_G1, 256, 0, stream>>>(x1, x2, w1t, a1t, h1b, as1, ad1);
    k_gat1  <<<2 * NB_GAT1, 256, 0, stream>>>(h1b, as1, ad1, cursor, col, b1, hL1);
    k_gemm2 <<<2 * NB_G2, 256, 0, stream>>>(hL1, W2, a2s, a2d, h2, as2, ad2);
    k_gat2e <<<N_NODES / 16, 256, 0, stream>>>(h2, as2, ad2, cursor, col, b2, out);
}

// Round 2
// 315.650 us; speedup vs baseline: 1.0768x; 1.0088x over previous
//
#include <hip/hip_runtime.h>
#include <hip/hip_bf16.h>

#define N_NODES 50000
#define N_EDGES 800000
#define F_INS   128
#define HIDDEN  16
#define HEADS   8
#define HO      128      // HEADS*HIDDEN
#define C_OUT   16
#define NEG_SLOPE 0.2f
#define SLOT    64       // fixed col slots per node; P(Poisson(16) > 64) ~ 1e-20
#define NB_G1   ((N_NODES + 63) / 64)     // 782 blocks for MFMA gemm1 (per graph)
#define NB_GAT1 ((N_NODES + 3) / 4)       // 12500 blocks for gat1 (per graph)
#define NB_G2   ((N_NODES + 16) / 16)     // 3126 blocks for gemm2 (per graph, covers dummy row)

// padded row counts / strides (dummy node index == N_NODES)
#define NP      50016                      // N_NODES rounded up (+dummy row), 16-aligned
#define AS_ST   ((size_t)NP * 8)           // floats per graph for as1/ad1
#define H1B_ST  ((size_t)NP * 64)          // u32 per graph for h1b (bf16 pairs)
#define HL1_ST  ((size_t)N_NODES * 64)     // u32 per graph for hL1
#define H2_ST   ((size_t)NP * 16)          // floats per graph for h2
#define AS2_ST  ((size_t)NP)               // floats per graph for as2/ad2

// ---- two-phase CSR build constants ----
#define NCLS     128                       // node classes; cls = (d*1342)>>19, <=391 nodes/class
#define CLS_MUL  1342u
#define CLS_SH   19
#define CAP      8192                      // bucket capacity per (graph,class); expect ~6256
#define CHUNK    2048                      // edges per k_bucket block (256 thr x 8)
#define NB_BKT   ((N_EDGES + CHUNK - 1) / CHUNK)   // 391 chunks per graph

typedef unsigned short u16;
typedef unsigned int   u32;
typedef int v4i __attribute__((ext_vector_type(4)));
typedef short bf16x8 __attribute__((ext_vector_type(8)));
typedef float f32x4 __attribute__((ext_vector_type(4)));

__device__ __forceinline__ float bf2f(u16 u) {
    union { u32 i; float f; } t; t.i = ((u32)u) << 16; return t.f;
}
__device__ __forceinline__ float bflo(u32 q) {
    union { u32 i; float f; } t; t.i = q << 16; return t.f;
}
__device__ __forceinline__ float bfhi(u32 q) {
    union { u32 i; float f; } t; t.i = q & 0xFFFF0000u; return t.f;
}
__device__ __forceinline__ u32 f2bf(float f) {
    union { float f; u32 i; } t; t.f = f;
    u32 x = t.i;
    u32 lsb = (x >> 16) & 1u;
    x += 0x7FFFu + lsb;
    return x >> 16;
}
// HW packed f32->bf16 RNE convert (same rounding as f2bf, 1 instr instead of ~10)
__device__ __forceinline__ u32 cvtpk(float lo, float hi) {
    u32 r;
    asm("v_cvt_pk_bf16_f32 %0, %1, %2" : "=v"(r) : "v"(lo), "v"(hi));
    return r;
}
__device__ __forceinline__ float lrelu(float t) {
    return fmaxf(t, NEG_SLOPE * t);   // exact leaky-relu: 0.2t>t iff t<0
}
__device__ __forceinline__ int cls_of(int d) { return (int)(((u32)d * CLS_MUL) >> CLS_SH); }
__host__ __device__ __forceinline__ int cls_base(int c) { return (int)(((u32)c * 524288u + (CLS_MUL - 1)) / CLS_MUL); }

// ---------------- prep: W1T bf16 [c][k] + A1T bf16 [n][k] (n=2h+{s,d}) ----------------
__global__ void k_wt(const float* __restrict__ W1, const float* __restrict__ a1s,
                     const float* __restrict__ a1d, u32* __restrict__ w1t,
                     u32* __restrict__ a1t) {
    int t = threadIdx.x;
    if (blockIdx.x < 32) {
        int e = blockIdx.x * 256 + t;    // 0..8191
        int c = e >> 6, kp = e & 63;
        float lo = W1[(2 * kp) * 128 + c];
        float hi = W1[(2 * kp + 1) * 128 + c];
        w1t[e] = (f2bf(hi) << 16) | f2bf(lo);
    } else {
        #pragma unroll
        for (int i = 0; i < 4; ++i) {
            int wi = t + i * 256;        // 0..1023
            int n = wi >> 6, kp = wi & 63;
            int h = n >> 1;
            const float* av = ((n & 1) ? a1d : a1s) + h * 16;
            float s0 = 0.f, s1 = 0.f;
            #pragma unroll
            for (int c = 0; c < 16; ++c) {
                s0 += W1[(2 * kp) * 128 + h * 16 + c] * av[c];
                s1 += W1[(2 * kp + 1) * 128 + h * 16 + c] * av[c];
            }
            a1t[wi] = (f2bf(s1) << 16) | f2bf(s0);
        }
    }
}

// ---------------- phase A: bucket edges by node-class (few global atomics) ----------------
__launch_bounds__(256)
__global__ void k_bucket(const int* __restrict__ ei0, const int* __restrict__ ei1,
                         int* __restrict__ gcur, u32* __restrict__ bucket) {
    __shared__ int cnt[NCLS];
    __shared__ int base[NCLS];
    int t = threadIdx.x;
    int g = blockIdx.x & 1;
    int chunk = blockIdx.x >> 1;
    int e0 = chunk * CHUNK + t * 8;
    bool act = e0 < N_EDGES;

    if (t < NCLS) cnt[t] = 0;
    __syncthreads();

    const int* src = g ? ei1 : ei0;
    const int* dst = src + N_EDGES;
    int d8[8], s8[8], c8[8];
    if (act) {
        v4i da = *(const v4i*)(dst + e0), db = *(const v4i*)(dst + e0 + 4);
        v4i sa = *(const v4i*)(src + e0), sb = *(const v4i*)(src + e0 + 4);
        d8[0]=da[0]; d8[1]=da[1]; d8[2]=da[2]; d8[3]=da[3];
        d8[4]=db[0]; d8[5]=db[1]; d8[6]=db[2]; d8[7]=db[3];
        s8[0]=sa[0]; s8[1]=sa[1]; s8[2]=sa[2]; s8[3]=sa[3];
        s8[4]=sb[0]; s8[5]=sb[1]; s8[6]=sb[2]; s8[7]=sb[3];
        #pragma unroll
        for (int j = 0; j < 8; ++j) {
            c8[j] = cls_of(d8[j]);
            atomicAdd(&cnt[c8[j]], 1);
        }
    }
    __syncthreads();
    if (t < NCLS) {
        int n = cnt[t];
        base[t] = n ? atomicAdd(&gcur[g * NCLS + t], n) : 0;
        cnt[t] = 0;
    }
    __syncthreads();
    if (act) {
        #pragma unroll
        for (int j = 0; j < 8; ++j) {
            int c = c8[j];
            int p = atomicAdd(&cnt[c], 1);
            bucket[(size_t)(g * NCLS + c) * CAP + base[c] + p] =
                ((u32)d8[j] << 16) | (u32)s8[j];
        }
    }
}

// ---------------- phase B: CSR build fully in LDS, coalesced dwordx4 flush ----------------
// Old version did scattered 2-byte global stores (heavy L2 RMW amplification); now the
// whole per-class col region (<=391*64*2B = 50 KB) is staged in LDS and written out linearly.
__launch_bounds__(256)
__global__ void k_build(const int* __restrict__ gcur, const u32* __restrict__ bucket,
                        int* __restrict__ cursor, u16* __restrict__ col) {
    __shared__ int cnt[391];
    __shared__ __align__(16) u16 scol[391 * SLOT];   // 50048 B
    int t = threadIdx.x;
    int c = blockIdx.x & (NCLS - 1);
    int g = blockIdx.x >> 7;
    int d0 = cls_base(c);
    int d1 = (c == NCLS - 1) ? N_NODES : cls_base(c + 1);
    int nn = d1 - d0;
    for (int j = t; j < nn; j += 256) cnt[j] = 0;
    __syncthreads();

    int size = gcur[g * NCLS + c];
    const u32* bp = bucket + (size_t)(g * NCLS + c) * CAP;
    for (int i = t; i < size; i += 256) {
        u32 e = bp[i];
        int d = (int)(e >> 16);
        int s = (int)(e & 0xFFFFu);
        int p = atomicAdd(&cnt[d - d0], 1);
        if (p < SLOT) scol[(d - d0) * SLOT + p] = (u16)s;
    }
    __syncthreads();
    int* cur = cursor + g * N_NODES;
    for (int j = t; j < nn; j += 256) {
        int raw = cnt[j];
        int n0 = min(raw, SLOT);
        int n1 = (n0 + 7) & ~7;            // pad to next multiple of 8 with dummy node
        for (int p = n0; p < n1; ++p) scol[j * SLOT + p] = (u16)N_NODES;
        cur[d0 + j] = raw;
    }
    __syncthreads();
    // coalesced flush: nn*8 uint4 (slots beyond pad carry unread garbage, same as before)
    uint4* dst = (uint4*)(col + ((size_t)g * N_NODES + d0) * SLOT);
    const uint4* srcv = (const uint4*)scol;
    int n16 = nn * 8;
    for (int i = t; i < n16; i += 256) dst[i] = srcv[i];
}

// ---------------- GEMM1 via MFMA, both graphs, writes dummy row N_NODES ----------------
__launch_bounds__(256)
__global__ void k_gemm1(const float* __restrict__ x1g, const float* __restrict__ x2g,
                        const u32* __restrict__ w1t, const u32* __restrict__ a1t,
                        u32* __restrict__ h1b, float* __restrict__ as_,
                        float* __restrict__ ad_) {
    __shared__ u32 xls[4096];   // 16 KB: [wid][kt][lane][jj]
    int t = threadIdx.x;
    int bid = blockIdx.x;
    int g = bid >= NB_G1;
    if (g) bid -= NB_G1;
    const float* x = g ? x2g : x1g;
    u32*   h1o = h1b + (size_t)g * H1B_ST;
    float* aso = as_ + (size_t)g * AS_ST;
    float* ado = ad_ + (size_t)g * AS_ST;
    int r0 = bid * 64;

    const float2* x2p = (const float2*)x;
    #pragma unroll
    for (int i = 0; i < 16; ++i) {
        int A = t + i * 256;
        int wi = A >> 10, kt = (A >> 8) & 3, L = (A >> 2) & 63, jj = A & 3;
        int m = L & 15, qd = L >> 4;
        int r = r0 + wi * 16 + m;
        int pp = kt * 16 + qd * 4 + jj;
        float2 v = make_float2(0.f, 0.f);
        if (r < N_NODES) v = x2p[(size_t)r * 64 + pp];
        xls[A] = cvtpk(v.x, v.y);
    }
    __syncthreads();

    int lane = t & 63;
    int wid = t >> 6;
    int n = lane & 15, quad = lane >> 4;

    f32x4 acc[8], acca;
    #pragma unroll
    for (int ct = 0; ct < 8; ++ct) acc[ct] = (f32x4){0.f, 0.f, 0.f, 0.f};
    acca = (f32x4){0.f, 0.f, 0.f, 0.f};

    #pragma unroll
    for (int kt = 0; kt < 4; ++kt) {
        union { uint4 u; bf16x8 v; } af;
        af.u = *(const uint4*)(xls + wid * 1024 + kt * 256 + lane * 4);
        #pragma unroll
        for (int ct = 0; ct < 8; ++ct) {
            union { uint4 u; bf16x8 v; } bf_;
            bf_.u = *(const uint4*)(w1t + (ct * 16 + n) * 64 + kt * 16 + quad * 4);
            acc[ct] = __builtin_amdgcn_mfma_f32_16x16x32_bf16(af.v, bf_.v, acc[ct], 0, 0, 0);
        }
        union { uint4 u; bf16x8 v; } ba;
        ba.u = *(const uint4*)(a1t + n * 64 + kt * 16 + quad * 4);
        acca = __builtin_amdgcn_mfma_f32_16x16x32_bf16(af.v, ba.v, acca, 0, 0, 0);
    }

    // C/D layout: col = lane&15, row = quad*4+reg [m89]
    int h = n >> 1;
    #pragma unroll
    for (int reg = 0; reg < 4; ++reg) {
        int gr = r0 + wid * 16 + quad * 4 + reg;
        bool ok = gr <= N_NODES;           // include dummy row
        float av = (gr == N_NODES) ? -1e30f : acca[reg];  // dummy: w=exp(leaky(-1e30+ad))=0
        if (ok) {
            if (n & 1) ado[gr * 8 + h] = av;
            else       aso[gr * 8 + h] = av;
        }
        #pragma unroll
        for (int ct = 0; ct < 8; ++ct) {
            float ot = __shfl_xor(acc[ct][reg], 1);
            if (!(n & 1) && ok)
                h1o[(size_t)gr * 64 + ct * 8 + (n >> 1)] = cvtpk(acc[ct][reg], ot);
        }
    }
}

// ---- k_gat1 pipeline macros: issue gathers for one 8-edge batch / consume it ----
#define GAT1_ISSUE(I, q0,q1,q2,q3,q4,q5,q6,q7, A) do { \
    u32 ix_=(I).x, iy_=(I).y, iz_=(I).z, iw_=(I).w; \
    q0 = *(const u32*)(h1c + (((ix_ & 0xFFFFu) << 8) | lane4)); \
    q1 = *(const u32*)(h1c + (((ix_ >> 16)     << 8) | lane4)); \
    q2 = *(const u32*)(h1c + (((iy_ & 0xFFFFu) << 8) | lane4)); \
    q3 = *(const u32*)(h1c + (((iy_ >> 16)     << 8) | lane4)); \
    q4 = *(const u32*)(h1c + (((iz_ & 0xFFFFu) << 8) | lane4)); \
    q5 = *(const u32*)(h1c + (((iz_ >> 16)     << 8) | lane4)); \
    q6 = *(const u32*)(h1c + (((iw_ & 0xFFFFu) << 8) | lane4)); \
    q7 = *(const u32*)(h1c + (((iw_ >> 16)     << 8) | lane4)); \
    u32 ds_ = (j8 & 4) ? ((j8 & 2) ? iw_ : iz_) : ((j8 & 2) ? iy_ : ix_); \
    u32 sA_ = (j8 & 1) ? (ds_ >> 16) : (ds_ & 0xFFFFu); \
    A = *(const float*)(asc + ((sA_ << 5) | ha4)); \
} while (0)

#define GAT1_CONS(q0,q1,q2,q3,q4,q5,q6,q7, A) do { \
    int wli_ = __float_as_int(__expf(lrelu((A) + ad_a))); \
    float w0 = __int_as_float(__builtin_amdgcn_ds_bpermute(vb,       wli_)); \
    float w1 = __int_as_float(__builtin_amdgcn_ds_bpermute(vb + 32,  wli_)); \
    float w2 = __int_as_float(__builtin_amdgcn_ds_bpermute(vb + 64,  wli_)); \
    float w3 = __int_as_float(__builtin_amdgcn_ds_bpermute(vb + 96,  wli_)); \
    float w4 = __int_as_float(__builtin_amdgcn_ds_bpermute(vb + 128, wli_)); \
    float w5 = __int_as_float(__builtin_amdgcn_ds_bpermute(vb + 160, wli_)); \
    float w6 = __int_as_float(__builtin_amdgcn_ds_bpermute(vb + 192, wli_)); \
    float w7 = __int_as_float(__builtin_amdgcn_ds_bpermute(vb + 224, wli_)); \
    denom += ((w0 + w1) + (w2 + w3)) + ((w4 + w5) + (w6 + w7)); \
    ax += w0 * bflo(q0) + w1 * bflo(q1) + w2 * bflo(q2) + w3 * bflo(q3) \
        + w4 * bflo(q4) + w5 * bflo(q5) + w6 * bflo(q6) + w7 * bflo(q7); \
    ay += w0 * bfhi(q0) + w1 * bfhi(q1) + w2 * bfhi(q2) + w3 * bfhi(q3) \
        + w4 * bfhi(q4) + w5 * bfhi(q5) + w6 * bfhi(q6) + w7 * bfhi(q7); \
} while (0)

// ---------------- GAT layer 1 gather: one wave per node, both graphs ----------------
// Latency-bound fix: 2-phase double-buffered pipeline. Indices prefetched 2 batches
// ahead (uint4), the 8 h1-gathers + alpha gather issued 1 batch ahead into the
// alternate register set, so each batch's ~500-cycle gather latency hides under the
// previous batch's exp/bpermute/FMA consume. Compiler emits counted vmcnt waits.
__launch_bounds__(256)
__global__ void k_gat1(const u32* __restrict__ h1b, const float* __restrict__ as_,
                       const float* __restrict__ ad_, const int* __restrict__ cursor,
                       const u16* __restrict__ col, const float* __restrict__ b1,
                       u32* __restrict__ hL1) {
    int t = threadIdx.x;
    int lane = t & 63;
    int bid = blockIdx.x;
    int g = bid >= NB_GAT1;
    if (g) bid -= NB_GAT1;
    int node = bid * 4 + (t >> 6);         // grid exact: 12500*4 == N_NODES

    const char*  h1c = (const char*)(h1b + (size_t)g * H1B_ST);
    const char*  asc = (const char*)(as_ + (size_t)g * AS_ST);
    const float* ad1 = ad_ + (size_t)g * AS_ST;
    const u16*   cp  = col + ((size_t)g * N_NODES + node) * SLOT;

    int hc = lane >> 3;                    // channel head (lane covers ch 2L,2L+1)
    int ha = lane & 7;                     // alpha-duty head
    int j8 = lane >> 3;                    // alpha-duty edge-in-batch
    int vb = hc << 2;                      // bpermute byte base: src lane j*8+hc
    u32 lane4 = (u32)lane << 2;
    u32 ha4 = (u32)ha << 2;

    float ad_a = ad1[node * 8 + ha];
    float as_c = as_[(size_t)g * AS_ST + node * 8 + hc];
    float ad_c = ad1[node * 8 + hc];

    // self loop
    float w = __expf(lrelu(as_c + ad_c));
    float denom = w;
    u32 q = *(const u32*)(h1c + (((u32)node << 8) | lane4));
    float ax = w * bflo(q), ay = w * bfhi(q);

    int deg = min(cursor[g * N_NODES + node], SLOT);
    int nb = (deg + 7) >> 3;               // padded CSR: exactly nb full batches
    if (nb) {
        u32 qa0,qa1,qa2,qa3,qa4,qa5,qa6,qa7;
        u32 qb0,qb1,qb2,qb3,qb4,qb5,qb6,qb7;
        float Aa, Ab;
        uint4 Ia, Ib;
        Ia = *(const uint4*)cp;
        GAT1_ISSUE(Ia, qa0,qa1,qa2,qa3,qa4,qa5,qa6,qa7, Aa);
        if (nb > 1) {
            Ib = *(const uint4*)(cp + 8);
            GAT1_ISSUE(Ib, qb0,qb1,qb2,qb3,qb4,qb5,qb6,qb7, Ab);
        }
        int b = 0;
        for (;;) {
            GAT1_CONS(qa0,qa1,qa2,qa3,qa4,qa5,qa6,qa7, Aa);
            if (++b >= nb) break;
            if (b + 1 < nb) {
                Ia = *(const uint4*)(cp + (b + 1) * 8);
                GAT1_ISSUE(Ia, qa0,qa1,qa2,qa3,qa4,qa5,qa6,qa7, Aa);
            }
            GAT1_CONS(qb0,qb1,qb2,qb3,qb4,qb5,qb6,qb7, Ab);
            if (++b >= nb) break;
            if (b + 1 < nb) {
                Ib = *(const uint4*)(cp + (b + 1) * 8);
                GAT1_ISSUE(Ib, qb0,qb1,qb2,qb3,qb4,qb5,qb6,qb7, Ab);
            }
        }
    }
    float inv = 1.f / (denom + 1e-16f);
    int c = lane * 2;
    float o0 = ax * inv + b1[c];
    float o1 = ay * inv + b1[c + 1];
    o0 = (o0 > 0.f) ? o0 : (__expf(o0) - 1.f);   // ELU
    o1 = (o1 > 0.f) ? o1 : (__expf(o1) - 1.f);
    hL1[(size_t)g * HL1_ST + (size_t)node * 64 + lane] = cvtpk(o0, o1);
}

// ---------------- GEMM2 (+fused alpha2), both graphs, writes dummy row ----------------
__launch_bounds__(256)
__global__ void k_gemm2(const u32* __restrict__ hL1, const float* __restrict__ W2,
                        const float* __restrict__ a2s, const float* __restrict__ a2d,
                        float* __restrict__ h2, float* __restrict__ as2,
                        float* __restrict__ ad2) {
    __shared__ float w2s[F_INS * C_OUT];  // 8 KB, [k][c]
    __shared__ float hs[16 * 136];        // padded stride 136
    int t = threadIdx.x;
    int bid = blockIdx.x;
    int g = bid >= NB_G2;
    if (g) bid -= NB_G2;
    const u16* hL = (const u16*)(hL1 + (size_t)g * HL1_ST);
    float* h2o  = h2  + (size_t)g * H2_ST;
    float* as2o = as2 + (size_t)g * AS2_ST;
    float* ad2o = ad2 + (size_t)g * AS2_ST;

    const float4* w4 = (const float4*)W2;     // 512 float4s
    #pragma unroll
    for (int i = 0; i < 2; ++i) {
        int idx = t + i * 256;
        ((float4*)w2s)[idx] = w4[idx];
    }
    int r0 = bid * 16;
    const ushort4* hg = (const ushort4*)hL;   // 32 ushort4 per row
    #pragma unroll
    for (int i = 0; i < 2; ++i) {
        int idx = t + i * 256;      // 0..511
        int r  = idx >> 5;          // 0..15
        int c4 = idx & 31;
        ushort4 qq = make_ushort4(0, 0, 0, 0);
        if (r0 + r < N_NODES) qq = hg[(size_t)(r0 + r) * 32 + c4];
        float4 v; v.x = bf2f(qq.x); v.y = bf2f(qq.y); v.z = bf2f(qq.z); v.w = bf2f(qq.w);
        *(float4*)(hs + r * 136 + c4 * 4) = v;
    }
    __syncthreads();

    int c = t & 15, r = t >> 4;
    float acc = 0.f;
    #pragma unroll 8
    for (int k = 0; k < F_INS; ++k) acc += hs[r * 136 + k] * w2s[k * C_OUT + c];
    int n = r0 + r;
    if (n <= N_NODES) h2o[(size_t)n * C_OUT + c] = acc;   // dummy row: acc==0

    // fused alpha2: 16-lane butterfly within each row group
    float sa = acc * a2s[c];
    float sd = acc * a2d[c];
    #pragma unroll
    for (int m = 1; m < 16; m <<= 1) {
        sa += __shfl_xor(sa, m);
        sd += __shfl_xor(sd, m);
    }
    if (c == 0 && n <= N_NODES) {
        as2o[n] = (n == N_NODES) ? -1e30f : sa;           // dummy: w=0
        ad2o[n] = sd;
    }
}

// ---- k_gat2 pipeline macros: 8-edge batch issue/consume with exp-lane-transpose ----
// Lane L (l4 = L&15) has duty edge jsel = L&7: computes the ONE exp chain + loads the
// ONE as2 value for it (vs 8 redundant chains x16 lanes before), then all lanes pull
// w_j via ds_bpermute within their 16-lane group.
#define GAT2_ISSUE(I, v0,v1,v2,v3,v4,v5,v6,v7, A) do { \
    u32 ix_=(I).x, iy_=(I).y, iz_=(I).z, iw_=(I).w; \
    v0 = *(const float*)(h2c + (((ix_ & 0xFFFFu) << 6) | c4)); \
    v1 = *(const float*)(h2c + (((ix_ >> 16)     << 6) | c4)); \
    v2 = *(const float*)(h2c + (((iy_ & 0xFFFFu) << 6) | c4)); \
    v3 = *(const float*)(h2c + (((iy_ >> 16)     << 6) | c4)); \
    v4 = *(const float*)(h2c + (((iz_ & 0xFFFFu) << 6) | c4)); \
    v5 = *(const float*)(h2c + (((iz_ >> 16)     << 6) | c4)); \
    v6 = *(const float*)(h2c + (((iw_ & 0xFFFFu) << 6) | c4)); \
    v7 = *(const float*)(h2c + (((iw_ >> 16)     << 6) | c4)); \
    u32 ds_ = (jsel & 4) ? ((jsel & 2) ? iw_ : iz_) : ((jsel & 2) ? iy_ : ix_); \
    u32 sA_ = (jsel & 1) ? (ds_ >> 16) : (ds_ & 0xFFFFu); \
    A = *(const float*)(as2c + (sA_ << 2)); \
} while (0)

#define GAT2_CONS(v0,v1,v2,v3,v4,v5,v6,v7, A) do { \
    int wli_ = __float_as_int(__expf(lrelu((A) + ad))); \
    float w0 = __int_as_float(__builtin_amdgcn_ds_bpermute(gb,      wli_)); \
    float w1 = __int_as_float(__builtin_amdgcn_ds_bpermute(gb + 4,  wli_)); \
    float w2 = __int_as_float(__builtin_amdgcn_ds_bpermute(gb + 8,  wli_)); \
    float w3 = __int_as_float(__builtin_amdgcn_ds_bpermute(gb + 12, wli_)); \
    float w4 = __int_as_float(__builtin_amdgcn_ds_bpermute(gb + 16, wli_)); \
    float w5 = __int_as_float(__builtin_amdgcn_ds_bpermute(gb + 20, wli_)); \
    float w6 = __int_as_float(__builtin_amdgcn_ds_bpermute(gb + 24, wli_)); \
    float w7 = __int_as_float(__builtin_amdgcn_ds_bpermute(gb + 28, wli_)); \
    denom += ((w0 + w1) + (w2 + w3)) + ((w4 + w5) + (w6 + w7)); \
    acc += (w0 * v0 + w1 * v1 + w2 * v2 + w3 * v3) \
         + (w4 * v4 + w5 * v5 + w6 * v6 + w7 * v7); \
} while (0)

__device__ __forceinline__ float gat2_node(const char* h2c, const char* as2c,
                                           const float* __restrict__ ad2g, int deg,
                                           const u16* __restrict__ cp, int node,
                                           u32 c4, int jsel, u32 gb, float b2c) {
    float ad = ad2g[node];
    float w = __expf(lrelu(*(const float*)(as2c + ((u32)node << 2)) + ad));
    float denom = w;
    float acc = w * *(const float*)(h2c + (((u32)node << 6) | c4));

    int nb = (deg + 7) >> 3;
    if (nb) {
        float va0,va1,va2,va3,va4,va5,va6,va7;
        float vc0,vc1,vc2,vc3,vc4,vc5,vc6,vc7;
        float Aa, Ac;
        uint4 Ia, Ic;
        Ia = *(const uint4*)cp;
        GAT2_ISSUE(Ia, va0,va1,va2,va3,va4,va5,va6,va7, Aa);
        if (nb > 1) {
            Ic = *(const uint4*)(cp + 8);
            GAT2_ISSUE(Ic, vc0,vc1,vc2,vc3,vc4,vc5,vc6,vc7, Ac);
        }
        int b = 0;
        for (;;) {
            GAT2_CONS(va0,va1,va2,va3,va4,va5,va6,va7, Aa);
            if (++b >= nb) break;
            if (b + 1 < nb) {
                Ia = *(const uint4*)(cp + (b + 1) * 8);
                GAT2_ISSUE(Ia, va0,va1,va2,va3,va4,va5,va6,va7, Aa);
            }
            GAT2_CONS(vc0,vc1,vc2,vc3,vc4,vc5,vc6,vc7, Ac);
            if (++b >= nb) break;
            if (b + 1 < nb) {
                Ic = *(const uint4*)(cp + (b + 1) * 8);
                GAT2_ISSUE(Ic, vc0,vc1,vc2,vc3,vc4,vc5,vc6,vc7, Ac);
            }
        }
    }
    return acc / (denom + 1e-16f) + b2c;
}

// ---------------- GAT layer 2 both graphs + fused epilogue ----------------
__launch_bounds__(256)
__global__ void k_gat2e(const float* __restrict__ h2, const float* __restrict__ as2,
                        const float* __restrict__ ad2, const int* __restrict__ cursor,
                        const u16* __restrict__ col, const float* __restrict__ b2,
                        float* __restrict__ out) {
    int t = threadIdx.x;
    int node = blockIdx.x * 16 + (t >> 4);   // grid exact: 3125*16 == N_NODES
    int c = t & 15;
    int lane = t & 63;
    u32 c4 = (u32)c << 2;
    int jsel = lane & 7;
    u32 gb = (u32)(lane & 48) << 2;          // bpermute group base byte
    float b2c = b2[c];

    int degY = min(cursor[node], SLOT);
    int degZ = min(cursor[N_NODES + node], SLOT);
    float yv = gat2_node((const char*)h2, (const char*)as2, ad2, degY,
                         col + (size_t)node * SLOT, node, c4, jsel, gb, b2c);
    float zv = gat2_node((const char*)(h2 + H2_ST), (const char*)(as2 + AS2_ST),
                         ad2 + AS2_ST, degZ,
                         col + ((size_t)N_NODES + node) * SLOT, node, c4, jsel, gb, b2c);

    float my = yv, mz = zv;
    #pragma unroll
    for (int m = 1; m < 16; m <<= 1) {
        my = fmaxf(my, __shfl_xor(my, m));
        mz = fmaxf(mz, __shfl_xor(mz, m));
    }
    float sy = __expf(yv - my), sz = __expf(zv - mz);
    float dot = yv * zv, ny = yv * yv, nz = zv * zv;
    #pragma unroll
    for (int m = 1; m < 16; m <<= 1) {
        sy  += __shfl_xor(sy, m);
        sz  += __shfl_xor(sz, m);
        dot += __shfl_xor(dot, m);
        ny  += __shfl_xor(ny, m);
        nz  += __shfl_xor(nz, m);
    }
    float lsey = my + __logf(sy);
    float lsez = mz + __logf(sz);
    float omc = 1.f - dot / (fmaxf(sqrtf(ny), 1e-8f) * fmaxf(sqrtf(nz), 1e-8f));

    const int O1 = N_NODES * C_OUT;            //  800000: 1-cos
    const int O2 = O1 + N_NODES;               //  850000: ls_z
    const int O3 = O2 + N_NODES * C_OUT;       // 1650000: ls_y
    const int O4 = O3 + N_NODES * C_OUT;       // 2450000: ls_y
    float ly = yv - lsey;
    float lz = zv - lsez;
    int base = node * 16 + c;
    out[base]      = ly;
    out[O2 + base] = lz;
    out[O3 + base] = ly;
    out[O4 + base] = ly;
    if (c == 0) out[O1 + node] = omc;
}

extern "C" void kernel_launch(void* const* d_in, const int* in_sizes, int n_in,
                              void* d_out, int out_size, void* d_ws, size_t ws_size,
                              hipStream_t stream) {
    (void)in_sizes; (void)n_in; (void)out_size; (void)ws_size;
    const float* x1  = (const float*)d_in[0];
    const int*   ei1 = (const int*)d_in[1];
    const float* x2  = (const float*)d_in[2];
    const int*   ei2 = (const int*)d_in[3];
    const float* W1  = (const float*)d_in[4];
    const float* a1s = (const float*)d_in[5];
    const float* a1d = (const float*)d_in[6];
    const float* b1  = (const float*)d_in[7];
    const float* W2  = (const float*)d_in[8];
    const float* a2s = (const float*)d_in[9];
    const float* a2d = (const float*)d_in[10];
    const float* b2  = (const float*)d_in[11];
    float* out = (float*)d_out;

    // Workspace layout: ~78 MB. bucket (8 MB) aliases h1b (25.6 MB):
    // consumed by k_build before k_gemm1 first writes h1b.
    char* p = (char*)d_ws;
    int* gcur      = (int*)p; p += (size_t)2 * NCLS * 4;             //   1 KB
    u32* w1t       = (u32*)p; p += (size_t)128 * 64 * 4;             //  32 KB (bf16 W1T [c][k])
    u32* a1t       = (u32*)p; p += (size_t)16 * 64 * 4;              //   4 KB (bf16 A1T [n][k])
    int* cursor    = (int*)p; p += (size_t)2 * N_NODES * 4;          //   0.4 MB
    u16* col       = (u16*)p; p += (size_t)2 * N_NODES * SLOT * 2;   //  12.8 MB
    float* as1  = (float*)p; p += (size_t)2 * AS_ST * 4;             //   3.2 MB
    float* ad1  = (float*)p; p += (size_t)2 * AS_ST * 4;             //   3.2 MB
    float* h2   = (float*)p; p += (size_t)2 * H2_ST * 4;             //   6.4 MB
    float* as2  = (float*)p; p += (size_t)2 * AS2_ST * 4;            //   0.4 MB
    float* ad2  = (float*)p; p += (size_t)2 * AS2_ST * 4;            //   0.4 MB
    u32* hL1    = (u32*)p;   p += (size_t)2 * HL1_ST * 4;            //  25.6 MB (bf16)
    u32* h1b    = (u32*)p;   p += (size_t)2 * H1B_ST * 4;            //  25.6 MB (bf16)
    u32* bucket = h1b;                                               //   8 MB alias

    hipMemsetAsync(gcur, 0, (size_t)2 * NCLS * 4, stream);
    k_wt    <<<33, 256, 0, stream>>>(W1, a1s, a1d, w1t, a1t);
    k_bucket<<<2 * NB_BKT, 256, 0, stream>>>(ei1, ei2, gcur, bucket);
    k_build <<<2 * NCLS, 256, 0, stream>>>(gcur, bucket, cursor, col);
    k_gemm1 <<<2 * NB_G1, 256, 0, stream>>>(x1, x2, w1t, a1t, h1b, as1, ad1);
    k_gat1  <<<2 * NB_GAT1, 256, 0, stream>>>(h1b, as1, ad1, cursor, col, b1, hL1);
    k_gemm2 <<<2 * NB_G2, 256, 0, stream>>>(hL1, W2, a2s, a2d, h2, as2, ad2);
    k_gat2e <<<N_NODES / 16, 256, 0, stream>>>(h2, as2, ad2, cursor, col, b2, out);
}

// Round 3
// 310.914 us; speedup vs baseline: 1.0932x; 1.0152x over previous
//
#include <hip/hip_runtime.h>
#include <hip/hip_bf16.h>

#define N_NODES 50000
#define N_EDGES 800000
#define F_INS   128
#define HIDDEN  16
#define HEADS   8
#define HO      128      // HEADS*HIDDEN
#define C_OUT   16
#define NEG_SLOPE 0.2f
#define SLOT    64       // fixed col slots per node; P(Poisson(16) > 64) ~ 1e-20
#define NB_G1   ((N_NODES + 63) / 64)     // 782 blocks for MFMA gemm1 (per graph)
#define NB_GAT1 ((N_NODES + 3) / 4)       // 12500 blocks for gat1 (per graph)
#define NB_G2   ((N_NODES + 16) / 16)     // 3126 blocks for gemm2 (per graph, covers dummy row)

// padded row counts / strides (dummy node index == N_NODES)
#define NP      50016                      // N_NODES rounded up (+dummy row), 16-aligned
#define AS_ST   ((size_t)NP * 8)           // floats per graph for as1/ad1
#define H1B_ST  ((size_t)NP * 64)          // u32 per graph for h1b (bf16 pairs)
#define HL1_ST  ((size_t)N_NODES * 64)     // u32 per graph for hL1
#define H2_ST   ((size_t)NP * 16)          // floats per graph for h2
#define AS2_ST  ((size_t)NP)               // floats per graph for as2/ad2

// ---- two-phase CSR build constants ----
#define NCLS     128                       // node classes; cls = (d*1342)>>19, <=391 nodes/class
#define CLS_MUL  1342u
#define CLS_SH   19
#define CAP      8192                      // bucket capacity per (graph,class); expect ~6256
#define CHUNK    2048                      // edges per bucket block (256 thr x 8)
#define NB_BKT   ((N_EDGES + CHUNK - 1) / CHUNK)   // 391 chunks per graph

typedef unsigned short u16;
typedef unsigned int   u32;
typedef int v4i __attribute__((ext_vector_type(4)));
typedef short bf16x8 __attribute__((ext_vector_type(8)));
typedef float f32x4 __attribute__((ext_vector_type(4)));

__device__ __forceinline__ float bf2f(u16 u) {
    union { u32 i; float f; } t; t.i = ((u32)u) << 16; return t.f;
}
__device__ __forceinline__ float bflo(u32 q) {
    union { u32 i; float f; } t; t.i = q << 16; return t.f;
}
__device__ __forceinline__ float bfhi(u32 q) {
    union { u32 i; float f; } t; t.i = q & 0xFFFF0000u; return t.f;
}
__device__ __forceinline__ u32 f2bf(float f) {
    union { float f; u32 i; } t; t.f = f;
    u32 x = t.i;
    u32 lsb = (x >> 16) & 1u;
    x += 0x7FFFu + lsb;
    return x >> 16;
}
// HW packed f32->bf16 RNE convert (same rounding as f2bf, 1 instr instead of ~10)
__device__ __forceinline__ u32 cvtpk(float lo, float hi) {
    u32 r;
    asm("v_cvt_pk_bf16_f32 %0, %1, %2" : "=v"(r) : "v"(lo), "v"(hi));
    return r;
}
__device__ __forceinline__ float lrelu(float t) {
    return fmaxf(t, NEG_SLOPE * t);   // exact leaky-relu: 0.2t>t iff t<0
}
__device__ __forceinline__ int cls_of(int d) { return (int)(((u32)d * CLS_MUL) >> CLS_SH); }
__host__ __device__ __forceinline__ int cls_base(int c) { return (int)(((u32)c * 524288u + (CLS_MUL - 1)) / CLS_MUL); }

// ---------------- prep: W1T bf16 [c][k] + A1T bf16 [n][k] + gcur zero ----------------
__global__ void k_wt(const float* __restrict__ W1, const float* __restrict__ a1s,
                     const float* __restrict__ a1d, u32* __restrict__ w1t,
                     u32* __restrict__ a1t, int* __restrict__ gcur) {
    int t = threadIdx.x;
    if (blockIdx.x < 32) {
        int e = blockIdx.x * 256 + t;    // 0..8191
        int c = e >> 6, kp = e & 63;
        float lo = W1[(2 * kp) * 128 + c];
        float hi = W1[(2 * kp + 1) * 128 + c];
        w1t[e] = (f2bf(hi) << 16) | f2bf(lo);
    } else {
        gcur[t] = 0;                     // 2*NCLS == 256, replaces hipMemsetAsync
        #pragma unroll
        for (int i = 0; i < 4; ++i) {
            int wi = t + i * 256;        // 0..1023
            int n = wi >> 6, kp = wi & 63;
            int h = n >> 1;
            const float* av = ((n & 1) ? a1d : a1s) + h * 16;
            float s0 = 0.f, s1 = 0.f;
            #pragma unroll
            for (int c = 0; c < 16; ++c) {
                s0 += W1[(2 * kp) * 128 + h * 16 + c] * av[c];
                s1 += W1[(2 * kp + 1) * 128 + h * 16 + c] * av[c];
            }
            a1t[wi] = (f2bf(s1) << 16) | f2bf(s0);
        }
    }
}

// ---------------- FAT: edge bucketing (blocks 0..781) + GEMM1 (blocks 782..2345) ----
// bucket depends only on gcur (k_wt); gemm1 only on w1t/a1t (k_wt) -> independent,
// merged into one launch: bucket's ~5us of edge streaming hides under gemm1.
// bucket[] aliases hL1 (first written later by k_gat1), NOT h1b (gemm1 writes it here).
__launch_bounds__(256)
__global__ void k_bg1(const int* __restrict__ ei0, const int* __restrict__ ei1,
                      int* __restrict__ gcur, u32* __restrict__ bucket,
                      const float* __restrict__ x1g, const float* __restrict__ x2g,
                      const u32* __restrict__ w1t, const u32* __restrict__ a1t,
                      u32* __restrict__ h1b, float* __restrict__ as_,
                      float* __restrict__ ad_) {
    __shared__ u32 xls[4096];   // 16 KB (gemm1 staging)
    __shared__ int cnt[NCLS];   // 1 KB (bucket)
    __shared__ int bse[NCLS];
    int t = threadIdx.x;

    if (blockIdx.x < 2 * NB_BKT) {
        // ---------------- bucket body ----------------
        int g = blockIdx.x & 1;
        int chunk = blockIdx.x >> 1;
        int e0 = chunk * CHUNK + t * 8;
        bool act = e0 < N_EDGES;

        if (t < NCLS) cnt[t] = 0;
        __syncthreads();

        const int* src = g ? ei1 : ei0;
        const int* dst = src + N_EDGES;
        int d8[8], s8[8], c8[8];
        if (act) {
            v4i da = *(const v4i*)(dst + e0), db = *(const v4i*)(dst + e0 + 4);
            v4i sa = *(const v4i*)(src + e0), sb = *(const v4i*)(src + e0 + 4);
            d8[0]=da[0]; d8[1]=da[1]; d8[2]=da[2]; d8[3]=da[3];
            d8[4]=db[0]; d8[5]=db[1]; d8[6]=db[2]; d8[7]=db[3];
            s8[0]=sa[0]; s8[1]=sa[1]; s8[2]=sa[2]; s8[3]=sa[3];
            s8[4]=sb[0]; s8[5]=sb[1]; s8[6]=sb[2]; s8[7]=sb[3];
            #pragma unroll
            for (int j = 0; j < 8; ++j) {
                c8[j] = cls_of(d8[j]);
                atomicAdd(&cnt[c8[j]], 1);
            }
        }
        __syncthreads();
        if (t < NCLS) {
            int n = cnt[t];
            bse[t] = n ? atomicAdd(&gcur[g * NCLS + t], n) : 0;
            cnt[t] = 0;
        }
        __syncthreads();
        if (act) {
            #pragma unroll
            for (int j = 0; j < 8; ++j) {
                int c = c8[j];
                int p = atomicAdd(&cnt[c], 1);
                bucket[(size_t)(g * NCLS + c) * CAP + bse[c] + p] =
                    ((u32)d8[j] << 16) | (u32)s8[j];
            }
        }
        return;
    }

    // ---------------- gemm1 body ----------------
    int bid = blockIdx.x - 2 * NB_BKT;
    int g = bid >= NB_G1;
    if (g) bid -= NB_G1;
    const float* x = g ? x2g : x1g;
    u32*   h1o = h1b + (size_t)g * H1B_ST;
    float* aso = as_ + (size_t)g * AS_ST;
    float* ado = ad_ + (size_t)g * AS_ST;
    int r0 = bid * 64;

    const float2* x2p = (const float2*)x;
    #pragma unroll
    for (int i = 0; i < 16; ++i) {
        int A = t + i * 256;
        int wi = A >> 10, kt = (A >> 8) & 3, L = (A >> 2) & 63, jj = A & 3;
        int m = L & 15, qd = L >> 4;
        int r = r0 + wi * 16 + m;
        int pp = kt * 16 + qd * 4 + jj;
        float2 v = make_float2(0.f, 0.f);
        if (r < N_NODES) v = x2p[(size_t)r * 64 + pp];
        xls[A] = cvtpk(v.x, v.y);
    }
    __syncthreads();

    int lane = t & 63;
    int wid = t >> 6;
    int n = lane & 15, quad = lane >> 4;

    f32x4 acc[8], acca;
    #pragma unroll
    for (int ct = 0; ct < 8; ++ct) acc[ct] = (f32x4){0.f, 0.f, 0.f, 0.f};
    acca = (f32x4){0.f, 0.f, 0.f, 0.f};

    #pragma unroll
    for (int kt = 0; kt < 4; ++kt) {
        union { uint4 u; bf16x8 v; } af;
        af.u = *(const uint4*)(xls + wid * 1024 + kt * 256 + lane * 4);
        #pragma unroll
        for (int ct = 0; ct < 8; ++ct) {
            union { uint4 u; bf16x8 v; } bf_;
            bf_.u = *(const uint4*)(w1t + (ct * 16 + n) * 64 + kt * 16 + quad * 4);
            acc[ct] = __builtin_amdgcn_mfma_f32_16x16x32_bf16(af.v, bf_.v, acc[ct], 0, 0, 0);
        }
        union { uint4 u; bf16x8 v; } ba;
        ba.u = *(const uint4*)(a1t + n * 64 + kt * 16 + quad * 4);
        acca = __builtin_amdgcn_mfma_f32_16x16x32_bf16(af.v, ba.v, acca, 0, 0, 0);
    }

    // C/D layout: col = lane&15, row = quad*4+reg [m89]
    int h = n >> 1;
    #pragma unroll
    for (int reg = 0; reg < 4; ++reg) {
        int gr = r0 + wid * 16 + quad * 4 + reg;
        bool ok = gr <= N_NODES;           // include dummy row
        float av = (gr == N_NODES) ? -1e30f : acca[reg];  // dummy: w=exp(leaky(-1e30+ad))=0
        if (ok) {
            if (n & 1) ado[gr * 8 + h] = av;
            else       aso[gr * 8 + h] = av;
        }
        #pragma unroll
        for (int ct = 0; ct < 8; ++ct) {
            float ot = __shfl_xor(acc[ct][reg], 1);
            if (!(n & 1) && ok)
                h1o[(size_t)gr * 64 + ct * 8 + (n >> 1)] = cvtpk(acc[ct][reg], ot);  // dummy row = 0
        }
    }
}

// ---------------- phase B: CSR build fully in LDS, coalesced dwordx4 flush ----------------
__launch_bounds__(256)
__global__ void k_build(const int* __restrict__ gcur, const u32* __restrict__ bucket,
                        int* __restrict__ cursor, u16* __restrict__ col) {
    __shared__ int cnt[391];
    __shared__ __align__(16) u16 scol[391 * SLOT];   // 50048 B
    int t = threadIdx.x;
    int c = blockIdx.x & (NCLS - 1);
    int g = blockIdx.x >> 7;
    int d0 = cls_base(c);
    int d1 = (c == NCLS - 1) ? N_NODES : cls_base(c + 1);
    int nn = d1 - d0;
    for (int j = t; j < nn; j += 256) cnt[j] = 0;
    __syncthreads();

    int size = gcur[g * NCLS + c];
    const u32* bp = bucket + (size_t)(g * NCLS + c) * CAP;
    for (int i = t; i < size; i += 256) {
        u32 e = bp[i];
        int d = (int)(e >> 16);
        int s = (int)(e & 0xFFFFu);
        int p = atomicAdd(&cnt[d - d0], 1);
        if (p < SLOT) scol[(d - d0) * SLOT + p] = (u16)s;
    }
    __syncthreads();
    int* cur = cursor + g * N_NODES;
    for (int j = t; j < nn; j += 256) {
        int raw = cnt[j];
        int n0 = min(raw, SLOT);
        int n1 = (n0 + 7) & ~7;            // pad to next multiple of 8 with dummy node
        for (int p = n0; p < n1; ++p) scol[j * SLOT + p] = (u16)N_NODES;
        cur[d0 + j] = raw;
    }
    __syncthreads();
    // coalesced flush: nn*8 uint4 (slots beyond pad carry unread garbage, same as before)
    uint4* dst = (uint4*)(col + ((size_t)g * N_NODES + d0) * SLOT);
    const uint4* srcv = (const uint4*)scol;
    int n16 = nn * 8;
    for (int i = t; i < n16; i += 256) dst[i] = srcv[i];
}

// ---- k_gat1 pipeline macros: issue gathers for one 8-edge batch / consume it ----
#define GAT1_ISSUE(I, q0,q1,q2,q3,q4,q5,q6,q7, A) do { \
    u32 ix_=(I).x, iy_=(I).y, iz_=(I).z, iw_=(I).w; \
    q0 = *(const u32*)(h1c + (((ix_ & 0xFFFFu) << 8) | lane4)); \
    q1 = *(const u32*)(h1c + (((ix_ >> 16)     << 8) | lane4)); \
    q2 = *(const u32*)(h1c + (((iy_ & 0xFFFFu) << 8) | lane4)); \
    q3 = *(const u32*)(h1c + (((iy_ >> 16)     << 8) | lane4)); \
    q4 = *(const u32*)(h1c + (((iz_ & 0xFFFFu) << 8) | lane4)); \
    q5 = *(const u32*)(h1c + (((iz_ >> 16)     << 8) | lane4)); \
    q6 = *(const u32*)(h1c + (((iw_ & 0xFFFFu) << 8) | lane4)); \
    q7 = *(const u32*)(h1c + (((iw_ >> 16)     << 8) | lane4)); \
    u32 ds_ = (j8 & 4) ? ((j8 & 2) ? iw_ : iz_) : ((j8 & 2) ? iy_ : ix_); \
    u32 sA_ = (j8 & 1) ? (ds_ >> 16) : (ds_ & 0xFFFFu); \
    A = *(const float*)(asc + ((sA_ << 5) | ha4)); \
} while (0)

#define GAT1_CONS(q0,q1,q2,q3,q4,q5,q6,q7, A) do { \
    int wli_ = __float_as_int(__expf(lrelu((A) + ad_a))); \
    float w0 = __int_as_float(__builtin_amdgcn_ds_bpermute(vb,       wli_)); \
    float w1 = __int_as_float(__builtin_amdgcn_ds_bpermute(vb + 32,  wli_)); \
    float w2 = __int_as_float(__builtin_amdgcn_ds_bpermute(vb + 64,  wli_)); \
    float w3 = __int_as_float(__builtin_amdgcn_ds_bpermute(vb + 96,  wli_)); \
    float w4 = __int_as_float(__builtin_amdgcn_ds_bpermute(vb + 128, wli_)); \
    float w5 = __int_as_float(__builtin_amdgcn_ds_bpermute(vb + 160, wli_)); \
    float w6 = __int_as_float(__builtin_amdgcn_ds_bpermute(vb + 192, wli_)); \
    float w7 = __int_as_float(__builtin_amdgcn_ds_bpermute(vb + 224, wli_)); \
    denom += ((w0 + w1) + (w2 + w3)) + ((w4 + w5) + (w6 + w7)); \
    ax += w0 * bflo(q0) + w1 * bflo(q1) + w2 * bflo(q2) + w3 * bflo(q3) \
        + w4 * bflo(q4) + w5 * bflo(q5) + w6 * bflo(q6) + w7 * bflo(q7); \
    ay += w0 * bfhi(q0) + w1 * bfhi(q1) + w2 * bfhi(q2) + w3 * bfhi(q3) \
        + w4 * bfhi(q4) + w5 * bfhi(q5) + w6 * bfhi(q6) + w7 * bfhi(q7); \
} while (0)

// ---------------- GAT layer 1 gather: one wave per node, both graphs (CONTROL: unchanged) ----
__launch_bounds__(256)
__global__ void k_gat1(const u32* __restrict__ h1b, const float* __restrict__ as_,
                       const float* __restrict__ ad_, const int* __restrict__ cursor,
                       const u16* __restrict__ col, const float* __restrict__ b1,
                       u32* __restrict__ hL1) {
    int t = threadIdx.x;
    int lane = t & 63;
    int bid = blockIdx.x;
    int g = bid >= NB_GAT1;
    if (g) bid -= NB_GAT1;
    int node = bid * 4 + (t >> 6);         // grid exact: 12500*4 == N_NODES

    const char*  h1c = (const char*)(h1b + (size_t)g * H1B_ST);
    const char*  asc = (const char*)(as_ + (size_t)g * AS_ST);
    const float* ad1 = ad_ + (size_t)g * AS_ST;
    const u16*   cp  = col + ((size_t)g * N_NODES + node) * SLOT;

    int hc = lane >> 3;                    // channel head (lane covers ch 2L,2L+1)
    int ha = lane & 7;                     // alpha-duty head
    int j8 = lane >> 3;                    // alpha-duty edge-in-batch
    int vb = hc << 2;                      // bpermute byte base: src lane j*8+hc
    u32 lane4 = (u32)lane << 2;
    u32 ha4 = (u32)ha << 2;

    float ad_a = ad1[node * 8 + ha];
    float as_c = as_[(size_t)g * AS_ST + node * 8 + hc];
    float ad_c = ad1[node * 8 + hc];

    // self loop
    float w = __expf(lrelu(as_c + ad_c));
    float denom = w;
    u32 q = *(const u32*)(h1c + (((u32)node << 8) | lane4));
    float ax = w * bflo(q), ay = w * bfhi(q);

    int deg = min(cursor[g * N_NODES + node], SLOT);
    int nb = (deg + 7) >> 3;               // padded CSR: exactly nb full batches
    if (nb) {
        u32 qa0,qa1,qa2,qa3,qa4,qa5,qa6,qa7;
        u32 qb0,qb1,qb2,qb3,qb4,qb5,qb6,qb7;
        float Aa, Ab;
        uint4 Ia, Ib;
        Ia = *(const uint4*)cp;
        GAT1_ISSUE(Ia, qa0,qa1,qa2,qa3,qa4,qa5,qa6,qa7, Aa);
        if (nb > 1) {
            Ib = *(const uint4*)(cp + 8);
            GAT1_ISSUE(Ib, qb0,qb1,qb2,qb3,qb4,qb5,qb6,qb7, Ab);
        }
        int b = 0;
        for (;;) {
            GAT1_CONS(qa0,qa1,qa2,qa3,qa4,qa5,qa6,qa7, Aa);
            if (++b >= nb) break;
            if (b + 1 < nb) {
                Ia = *(const uint4*)(cp + (b + 1) * 8);
                GAT1_ISSUE(Ia, qa0,qa1,qa2,qa3,qa4,qa5,qa6,qa7, Aa);
            }
            GAT1_CONS(qb0,qb1,qb2,qb3,qb4,qb5,qb6,qb7, Ab);
            if (++b >= nb) break;
            if (b + 1 < nb) {
                Ib = *(const uint4*)(cp + (b + 1) * 8);
                GAT1_ISSUE(Ib, qb0,qb1,qb2,qb3,qb4,qb5,qb6,qb7, Ab);
            }
        }
    }
    float inv = 1.f / (denom + 1e-16f);
    int c = lane * 2;
    float o0 = ax * inv + b1[c];
    float o1 = ay * inv + b1[c + 1];
    o0 = (o0 > 0.f) ? o0 : (__expf(o0) - 1.f);   // ELU
    o1 = (o1 > 0.f) ? o1 : (__expf(o1) - 1.f);
    hL1[(size_t)g * HL1_ST + (size_t)node * 64 + lane] = cvtpk(o0, o1);
}

// ---------------- GEMM2 (+fused alpha2), both graphs, writes dummy row ----------------
__launch_bounds__(256)
__global__ void k_gemm2(const u32* __restrict__ hL1, const float* __restrict__ W2,
                        const float* __restrict__ a2s, const float* __restrict__ a2d,
                        float* __restrict__ h2, float* __restrict__ as2,
                        float* __restrict__ ad2) {
    __shared__ float w2s[F_INS * C_OUT];  // 8 KB, [k][c]
    __shared__ float hs[16 * 136];        // padded stride 136
    int t = threadIdx.x;
    int bid = blockIdx.x;
    int g = bid >= NB_G2;
    if (g) bid -= NB_G2;
    const u16* hL = (const u16*)(hL1 + (size_t)g * HL1_ST);
    float* h2o  = h2  + (size_t)g * H2_ST;
    float* as2o = as2 + (size_t)g * AS2_ST;
    float* ad2o = ad2 + (size_t)g * AS2_ST;

    const float4* w4 = (const float4*)W2;     // 512 float4s
    #pragma unroll
    for (int i = 0; i < 2; ++i) {
        int idx = t + i * 256;
        ((float4*)w2s)[idx] = w4[idx];
    }
    int r0 = bid * 16;
    const ushort4* hg = (const ushort4*)hL;   // 32 ushort4 per row
    #pragma unroll
    for (int i = 0; i < 2; ++i) {
        int idx = t + i * 256;      // 0..511
        int r  = idx >> 5;          // 0..15
        int c4 = idx & 31;
        ushort4 qq = make_ushort4(0, 0, 0, 0);
        if (r0 + r < N_NODES) qq = hg[(size_t)(r0 + r) * 32 + c4];
        float4 v; v.x = bf2f(qq.x); v.y = bf2f(qq.y); v.z = bf2f(qq.z); v.w = bf2f(qq.w);
        *(float4*)(hs + r * 136 + c4 * 4) = v;
    }
    __syncthreads();

    int c = t & 15, r = t >> 4;
    float acc = 0.f;
    #pragma unroll 8
    for (int k = 0; k < F_INS; ++k) acc += hs[r * 136 + k] * w2s[k * C_OUT + c];
    int n = r0 + r;
    if (n <= N_NODES) h2o[(size_t)n * C_OUT + c] = acc;   // dummy row: acc==0

    // fused alpha2: 16-lane butterfly within each row group
    float sa = acc * a2s[c];
    float sd = acc * a2d[c];
    #pragma unroll
    for (int m = 1; m < 16; m <<= 1) {
        sa += __shfl_xor(sa, m);
        sd += __shfl_xor(sd, m);
    }
    if (c == 0 && n <= N_NODES) {
        as2o[n] = (n == N_NODES) ? -1e30f : sa;           // dummy: w=0
        ad2o[n] = sd;
    }
}

// ---- k_gat2 pipeline macros (parameterized by stream) ----
#define G2_ISSUE(I, H2C, ASC, v0,v1,v2,v3,v4,v5,v6,v7, A) do { \
    u32 ix_=(I).x, iy_=(I).y, iz_=(I).z, iw_=(I).w; \
    v0 = *(const float*)((H2C) + (((ix_ & 0xFFFFu) << 6) | c4)); \
    v1 = *(const float*)((H2C) + (((ix_ >> 16)     << 6) | c4)); \
    v2 = *(const float*)((H2C) + (((iy_ & 0xFFFFu) << 6) | c4)); \
    v3 = *(const float*)((H2C) + (((iy_ >> 16)     << 6) | c4)); \
    v4 = *(const float*)((H2C) + (((iz_ & 0xFFFFu) << 6) | c4)); \
    v5 = *(const float*)((H2C) + (((iz_ >> 16)     << 6) | c4)); \
    v6 = *(const float*)((H2C) + (((iw_ & 0xFFFFu) << 6) | c4)); \
    v7 = *(const float*)((H2C) + (((iw_ >> 16)     << 6) | c4)); \
    u32 ds_ = (jsel & 4) ? ((jsel & 2) ? iw_ : iz_) : ((jsel & 2) ? iy_ : ix_); \
    u32 sA_ = (jsel & 1) ? (ds_ >> 16) : (ds_ & 0xFFFFu); \
    A = *(const float*)((ASC) + (sA_ << 2)); \
} while (0)

#define G2_CONS(v0,v1,v2,v3,v4,v5,v6,v7, A, AD, DEN, ACC) do { \
    int wli_ = __float_as_int(__expf(lrelu((A) + (AD)))); \
    float w0 = __int_as_float(__builtin_amdgcn_ds_bpermute(gb,      wli_)); \
    float w1 = __int_as_float(__builtin_amdgcn_ds_bpermute(gb + 4,  wli_)); \
    float w2 = __int_as_float(__builtin_amdgcn_ds_bpermute(gb + 8,  wli_)); \
    float w3 = __int_as_float(__builtin_amdgcn_ds_bpermute(gb + 12, wli_)); \
    float w4 = __int_as_float(__builtin_amdgcn_ds_bpermute(gb + 16, wli_)); \
    float w5 = __int_as_float(__builtin_amdgcn_ds_bpermute(gb + 20, wli_)); \
    float w6 = __int_as_float(__builtin_amdgcn_ds_bpermute(gb + 24, wli_)); \
    float w7 = __int_as_float(__builtin_amdgcn_ds_bpermute(gb + 28, wli_)); \
    DEN += ((w0 + w1) + (w2 + w3)) + ((w4 + w5) + (w6 + w7)); \
    ACC += (w0 * v0 + w1 * v1 + w2 * v2 + w3 * v3) \
         + (w4 * v4 + w5 * v5 + w6 * v6 + w7 * v7); \
} while (0)

// ---------------- GAT layer 2 both graphs + fused epilogue ----------------
// y/z streams interleaved at batch granularity: h2/as2 are L2-resident (3.2/0.2 MB
// per graph < 4 MB XCD L2), so this kernel is L2-LATENCY-bound -> 2x memory-level
// parallelism from running both graphs' gather chains concurrently.
__launch_bounds__(256)
__global__ void k_gat2e(const float* __restrict__ h2, const float* __restrict__ as2,
                        const float* __restrict__ ad2, const int* __restrict__ cursor,
                        const u16* __restrict__ col, const float* __restrict__ b2,
                        float* __restrict__ out) {
    int t = threadIdx.x;
    int node = blockIdx.x * 16 + (t >> 4);   // grid exact: 3125*16 == N_NODES
    int c = t & 15;
    int lane = t & 63;
    u32 c4 = (u32)c << 2;
    int jsel = lane & 7;
    u32 gb = (u32)(lane & 48) << 2;          // bpermute group base byte
    float b2c = b2[c];

    const char* h2Y = (const char*)h2;
    const char* h2Z = (const char*)(h2 + H2_ST);
    const char* asY = (const char*)as2;
    const char* asZ = (const char*)(as2 + AS2_ST);
    const u16* cpY = col + (size_t)node * SLOT;
    const u16* cpZ = col + ((size_t)N_NODES + node) * SLOT;
    float adY = ad2[node];
    float adZ = ad2[AS2_ST + node];

    // self loops
    float wY = __expf(lrelu(*(const float*)(asY + ((u32)node << 2)) + adY));
    float dY = wY;
    float aY = wY * *(const float*)(h2Y + (((u32)node << 6) | c4));
    float wZ = __expf(lrelu(*(const float*)(asZ + ((u32)node << 2)) + adZ));
    float dZ = wZ;
    float aZ = wZ * *(const float*)(h2Z + (((u32)node << 6) | c4));

    int nbY = (min(cursor[node], SLOT) + 7) >> 3;
    int nbZ = (min(cursor[N_NODES + node], SLOT) + 7) >> 3;

    float y0,y1,y2,y3,y4,y5,y6,y7, Ay;
    float z0,z1,z2,z3,z4,z5,z6,z7, Az;
    uint4 I;
    if (nbY) { I = *(const uint4*)cpY; G2_ISSUE(I, h2Y, asY, y0,y1,y2,y3,y4,y5,y6,y7, Ay); }
    if (nbZ) { I = *(const uint4*)cpZ; G2_ISSUE(I, h2Z, asZ, z0,z1,z2,z3,z4,z5,z6,z7, Az); }
    int bY = 0, bZ = 0;
    while (bY < nbY || bZ < nbZ) {
        if (bY < nbY) {
            G2_CONS(y0,y1,y2,y3,y4,y5,y6,y7, Ay, adY, dY, aY);
            ++bY;
            if (bY < nbY) {
                I = *(const uint4*)(cpY + bY * 8);
                G2_ISSUE(I, h2Y, asY, y0,y1,y2,y3,y4,y5,y6,y7, Ay);
            }
        }
        if (bZ < nbZ) {
            G2_CONS(z0,z1,z2,z3,z4,z5,z6,z7, Az, adZ, dZ, aZ);
            ++bZ;
            if (bZ < nbZ) {
                I = *(const uint4*)(cpZ + bZ * 8);
                G2_ISSUE(I, h2Z, asZ, z0,z1,z2,z3,z4,z5,z6,z7, Az);
            }
        }
    }
    float yv = aY / (dY + 1e-16f) + b2c;
    float zv = aZ / (dZ + 1e-16f) + b2c;

    float my = yv, mz = zv;
    #pragma unroll
    for (int m = 1; m < 16; m <<= 1) {
        my = fmaxf(my, __shfl_xor(my, m));
        mz = fmaxf(mz, __shfl_xor(mz, m));
    }
    float sy = __expf(yv - my), sz = __expf(zv - mz);
    float dot = yv * zv, ny = yv * yv, nz = zv * zv;
    #pragma unroll
    for (int m = 1; m < 16; m <<= 1) {
        sy  += __shfl_xor(sy, m);
        sz  += __shfl_xor(sz, m);
        dot += __shfl_xor(dot, m);
        ny  += __shfl_xor(ny, m);
        nz  += __shfl_xor(nz, m);
    }
    float lsey = my + __logf(sy);
    float lsez = mz + __logf(sz);
    float omc = 1.f - dot / (fmaxf(sqrtf(ny), 1e-8f) * fmaxf(sqrtf(nz), 1e-8f));

    const int O1 = N_NODES * C_OUT;            //  800000: 1-cos
    const int O2 = O1 + N_NODES;               //  850000: ls_z
    const int O3 = O2 + N_NODES * C_OUT;       // 1650000: ls_y
    const int O4 = O3 + N_NODES * C_OUT;       // 2450000: ls_y
    float ly = yv - lsey;
    float lz = zv - lsez;
    int base = node * 16 + c;
    out[base]      = ly;
    out[O2 + base] = lz;
    out[O3 + base] = ly;
    out[O4 + base] = ly;
    if (c == 0) out[O1 + node] = omc;
}

extern "C" void kernel_launch(void* const* d_in, const int* in_sizes, int n_in,
                              void* d_out, int out_size, void* d_ws, size_t ws_size,
                              hipStream_t stream) {
    (void)in_sizes; (void)n_in; (void)out_size; (void)ws_size;
    const float* x1  = (const float*)d_in[0];
    const int*   ei1 = (const int*)d_in[1];
    const float* x2  = (const float*)d_in[2];
    const int*   ei2 = (const int*)d_in[3];
    const float* W1  = (const float*)d_in[4];
    const float* a1s = (const float*)d_in[5];
    const float* a1d = (const float*)d_in[6];
    const float* b1  = (const float*)d_in[7];
    const float* W2  = (const float*)d_in[8];
    const float* a2s = (const float*)d_in[9];
    const float* a2d = (const float*)d_in[10];
    const float* b2  = (const float*)d_in[11];
    float* out = (float*)d_out;

    // Workspace layout: ~78 MB. bucket (8 MB) aliases hL1 (25.6 MB): bucket is
    // consumed by k_build (L3) before k_gat1 (L4) first writes hL1. NOT h1b:
    // k_bg1 writes h1b (gemm1 half) concurrently with bucket writes.
    char* p = (char*)d_ws;
    int* gcur      = (int*)p; p += (size_t)2 * NCLS * 4;             //   1 KB
    u32* w1t       = (u32*)p; p += (size_t)128 * 64 * 4;             //  32 KB (bf16 W1T [c][k])
    u32* a1t       = (u32*)p; p += (size_t)16 * 64 * 4;              //   4 KB (bf16 A1T [n][k])
    int* cursor    = (int*)p; p += (size_t)2 * N_NODES * 4;          //   0.4 MB
    u16* col       = (u16*)p; p += (size_t)2 * N_NODES * SLOT * 2;   //  12.8 MB
    float* as1  = (float*)p; p += (size_t)2 * AS_ST * 4;             //   3.2 MB
    float* ad1  = (float*)p; p += (size_t)2 * AS_ST * 4;             //   3.2 MB
    float* h2   = (float*)p; p += (size_t)2 * H2_ST * 4;             //   6.4 MB
    float* as2  = (float*)p; p += (size_t)2 * AS2_ST * 4;            //   0.4 MB
    float* ad2  = (float*)p; p += (size_t)2 * AS2_ST * 4;            //   0.4 MB
    u32* hL1    = (u32*)p;   p += (size_t)2 * HL1_ST * 4;            //  25.6 MB (bf16)
    u32* h1b    = (u32*)p;   p += (size_t)2 * H1B_ST * 4;            //  25.6 MB (bf16)
    u32* bucket = hL1;                                               //   8 MB alias

    k_wt    <<<33, 256, 0, stream>>>(W1, a1s, a1d, w1t, a1t, gcur);
    k_bg1   <<<2 * NB_BKT + 2 * NB_G1, 256, 0, stream>>>(ei1, ei2, gcur, bucket,
                                                         x1, x2, w1t, a1t, h1b, as1, ad1);
    k_build <<<2 * NCLS, 256, 0, stream>>>(gcur, bucket, cursor, col);
    k_gat1  <<<2 * NB_GAT1, 256, 0, stream>>>(h1b, as1, ad1, cursor, col, b1, hL1);
    k_gemm2 <<<2 * NB_G2, 256, 0, stream>>>(hL1, W2, a2s, a2d, h2, as2, ad2);
    k_gat2e <<<N_NODES / 16, 256, 0, stream>>>(h2, as2, ad2, cursor, col, b2, out);
}

// Round 4
// 306.244 us; speedup vs baseline: 1.1099x; 1.0152x over previous
//
#include <hip/hip_runtime.h>
#include <hip/hip_bf16.h>

#define N_NODES 50000
#define N_EDGES 800000
#define F_INS   128
#define HIDDEN  16
#define HEADS   8
#define HO      128      // HEADS*HIDDEN
#define C_OUT   16
#define NEG_SLOPE 0.2f
#define SLOT    64       // fixed col slots per node; P(Poisson(16) > 64) ~ 1e-20
#define NB_G1   ((N_NODES + 63) / 64)     // 782 blocks for MFMA gemm1 (per graph)
#define NB_GAT1 ((N_NODES + 3) / 4)       // 12500 blocks for gat1 (per graph)
#define NB_G2   ((N_NODES + 16) / 16)     // 3126 blocks for gemm2 (per graph, covers dummy row)

// padded row counts / strides (dummy node index == N_NODES)
#define NP      50016                      // N_NODES rounded up (+dummy row), 16-aligned
#define AS_ST   ((size_t)NP * 8)           // floats per graph for as1/ad1
#define H1B_ST  ((size_t)NP * 64)          // u32 per graph for h1b (bf16 pairs)
#define HL1_ST  ((size_t)N_NODES * 64)     // u32 per graph for hL1
#define H2_ST   ((size_t)NP * 16)          // floats per graph for h2
#define AS2_ST  ((size_t)NP)               // floats per graph for as2/ad2

// ---- two-phase CSR build constants ----
#define NCLS     128                       // node classes; cls = (d*1342)>>19, <=391 nodes/class
#define CLS_MUL  1342u
#define CLS_SH   19
#define CAP      8192                      // bucket capacity per (graph,class); expect ~6256
#define CHUNK    2048                      // edges per bucket block (256 thr x 8)
#define NB_BKT   ((N_EDGES + CHUNK - 1) / CHUNK)   // 391 chunks per graph
#define GPAD     16                        // gcur stride: 1 counter per 64B cache line
                                           // (100K returning atomics into 4 lines was ~50us
                                           //  of L2-slice serialization; 256 lines -> parallel)

typedef unsigned short u16;
typedef unsigned int   u32;
typedef int v4i __attribute__((ext_vector_type(4)));
typedef short bf16x8 __attribute__((ext_vector_type(8)));
typedef float f32x4 __attribute__((ext_vector_type(4)));

__device__ __forceinline__ float bf2f(u16 u) {
    union { u32 i; float f; } t; t.i = ((u32)u) << 16; return t.f;
}
__device__ __forceinline__ float bflo(u32 q) {
    union { u32 i; float f; } t; t.i = q << 16; return t.f;
}
__device__ __forceinline__ float bfhi(u32 q) {
    union { u32 i; float f; } t; t.i = q & 0xFFFF0000u; return t.f;
}
__device__ __forceinline__ u32 f2bf(float f) {
    union { float f; u32 i; } t; t.f = f;
    u32 x = t.i;
    u32 lsb = (x >> 16) & 1u;
    x += 0x7FFFu + lsb;
    return x >> 16;
}
// HW packed f32->bf16 RNE convert (same rounding as f2bf, 1 instr instead of ~10)
__device__ __forceinline__ u32 cvtpk(float lo, float hi) {
    u32 r;
    asm("v_cvt_pk_bf16_f32 %0, %1, %2" : "=v"(r) : "v"(lo), "v"(hi));
    return r;
}
__device__ __forceinline__ float lrelu(float t) {
    return fmaxf(t, NEG_SLOPE * t);   // exact leaky-relu: 0.2t>t iff t<0
}
__device__ __forceinline__ int cls_of(int d) { return (int)(((u32)d * CLS_MUL) >> CLS_SH); }
__host__ __device__ __forceinline__ int cls_base(int c) { return (int)(((u32)c * 524288u + (CLS_MUL - 1)) / CLS_MUL); }

// ---------------- prep: W1T bf16 [c][k] + A1T bf16 [n][k] + gcur zero ----------------
__global__ void k_wt(const float* __restrict__ W1, const float* __restrict__ a1s,
                     const float* __restrict__ a1d, u32* __restrict__ w1t,
                     u32* __restrict__ a1t, int* __restrict__ gcur) {
    int t = threadIdx.x;
    if (blockIdx.x < 32) {
        int e = blockIdx.x * 256 + t;    // 0..8191
        int c = e >> 6, kp = e & 63;
        float lo = W1[(2 * kp) * 128 + c];
        float hi = W1[(2 * kp + 1) * 128 + c];
        w1t[e] = (f2bf(hi) << 16) | f2bf(lo);
    } else {
        #pragma unroll
        for (int i = 0; i < GPAD; ++i) gcur[t * GPAD + i] = 0;   // 2*NCLS*GPAD == 4096 ints
        #pragma unroll
        for (int i = 0; i < 4; ++i) {
            int wi = t + i * 256;        // 0..1023
            int n = wi >> 6, kp = wi & 63;
            int h = n >> 1;
            const float* av = ((n & 1) ? a1d : a1s) + h * 16;
            float s0 = 0.f, s1 = 0.f;
            #pragma unroll
            for (int c = 0; c < 16; ++c) {
                s0 += W1[(2 * kp) * 128 + h * 16 + c] * av[c];
                s1 += W1[(2 * kp + 1) * 128 + h * 16 + c] * av[c];
            }
            a1t[wi] = (f2bf(s1) << 16) | f2bf(s0);
        }
    }
}

// ---------------- FAT: edge bucketing (blocks 0..781) + GEMM1 (blocks 782..2345) ----
// bucket depends only on gcur (k_wt); gemm1 only on w1t/a1t (k_wt) -> independent,
// merged into one launch. bucket[] aliases hL1 (first written later by k_gat1).
__launch_bounds__(256)
__global__ void k_bg1(const int* __restrict__ ei0, const int* __restrict__ ei1,
                      int* __restrict__ gcur, u32* __restrict__ bucket,
                      const float* __restrict__ x1g, const float* __restrict__ x2g,
                      const u32* __restrict__ w1t, const u32* __restrict__ a1t,
                      u32* __restrict__ h1b, float* __restrict__ as_,
                      float* __restrict__ ad_) {
    __shared__ u32 xls[4096];   // 16 KB (gemm1 staging)
    __shared__ int cnt[NCLS];   // 1 KB (bucket)
    __shared__ int bse[NCLS];
    int t = threadIdx.x;

    if (blockIdx.x < 2 * NB_BKT) {
        // ---------------- bucket body ----------------
        int g = blockIdx.x & 1;
        int chunk = blockIdx.x >> 1;
        int e0 = chunk * CHUNK + t * 8;
        bool act = e0 < N_EDGES;

        if (t < NCLS) cnt[t] = 0;
        __syncthreads();

        const int* src = g ? ei1 : ei0;
        const int* dst = src + N_EDGES;
        int d8[8], s8[8], c8[8];
        if (act) {
            v4i da = *(const v4i*)(dst + e0), db = *(const v4i*)(dst + e0 + 4);
            v4i sa = *(const v4i*)(src + e0), sb = *(const v4i*)(src + e0 + 4);
            d8[0]=da[0]; d8[1]=da[1]; d8[2]=da[2]; d8[3]=da[3];
            d8[4]=db[0]; d8[5]=db[1]; d8[6]=db[2]; d8[7]=db[3];
            s8[0]=sa[0]; s8[1]=sa[1]; s8[2]=sa[2]; s8[3]=sa[3];
            s8[4]=sb[0]; s8[5]=sb[1]; s8[6]=sb[2]; s8[7]=sb[3];
            #pragma unroll
            for (int j = 0; j < 8; ++j) {
                c8[j] = cls_of(d8[j]);
                atomicAdd(&cnt[c8[j]], 1);
            }
        }
        __syncthreads();
        if (t < NCLS) {
            int n = cnt[t];
            bse[t] = n ? atomicAdd(&gcur[(g * NCLS + t) * GPAD], n) : 0;
            cnt[t] = 0;
        }
        __syncthreads();
        if (act) {
            #pragma unroll
            for (int j = 0; j < 8; ++j) {
                int c = c8[j];
                int p = atomicAdd(&cnt[c], 1);
                bucket[(size_t)(g * NCLS + c) * CAP + bse[c] + p] =
                    ((u32)d8[j] << 16) | (u32)s8[j];
            }
        }
        return;
    }

    // ---------------- gemm1 body ----------------
    int bid = blockIdx.x - 2 * NB_BKT;
    int g = bid >= NB_G1;
    if (g) bid -= NB_G1;
    const float* x = g ? x2g : x1g;
    u32*   h1o = h1b + (size_t)g * H1B_ST;
    float* aso = as_ + (size_t)g * AS_ST;
    float* ado = ad_ + (size_t)g * AS_ST;
    int r0 = bid * 64;

    const float2* x2p = (const float2*)x;
    #pragma unroll
    for (int i = 0; i < 16; ++i) {
        int A = t + i * 256;
        int wi = A >> 10, kt = (A >> 8) & 3, L = (A >> 2) & 63, jj = A & 3;
        int m = L & 15, qd = L >> 4;
        int r = r0 + wi * 16 + m;
        int pp = kt * 16 + qd * 4 + jj;
        float2 v = make_float2(0.f, 0.f);
        if (r < N_NODES) v = x2p[(size_t)r * 64 + pp];
        xls[A] = cvtpk(v.x, v.y);
    }
    __syncthreads();

    int lane = t & 63;
    int wid = t >> 6;
    int n = lane & 15, quad = lane >> 4;

    f32x4 acc[8], acca;
    #pragma unroll
    for (int ct = 0; ct < 8; ++ct) acc[ct] = (f32x4){0.f, 0.f, 0.f, 0.f};
    acca = (f32x4){0.f, 0.f, 0.f, 0.f};

    #pragma unroll
    for (int kt = 0; kt < 4; ++kt) {
        union { uint4 u; bf16x8 v; } af;
        af.u = *(const uint4*)(xls + wid * 1024 + kt * 256 + lane * 4);
        #pragma unroll
        for (int ct = 0; ct < 8; ++ct) {
            union { uint4 u; bf16x8 v; } bf_;
            bf_.u = *(const uint4*)(w1t + (ct * 16 + n) * 64 + kt * 16 + quad * 4);
            acc[ct] = __builtin_amdgcn_mfma_f32_16x16x32_bf16(af.v, bf_.v, acc[ct], 0, 0, 0);
        }
        union { uint4 u; bf16x8 v; } ba;
        ba.u = *(const uint4*)(a1t + n * 64 + kt * 16 + quad * 4);
        acca = __builtin_amdgcn_mfma_f32_16x16x32_bf16(af.v, ba.v, acca, 0, 0, 0);
    }

    // C/D layout: col = lane&15, row = quad*4+reg [m89]
    int h = n >> 1;
    #pragma unroll
    for (int reg = 0; reg < 4; ++reg) {
        int gr = r0 + wid * 16 + quad * 4 + reg;
        bool ok = gr <= N_NODES;           // include dummy row
        float av = (gr == N_NODES) ? -1e30f : acca[reg];  // dummy: w=exp(leaky(-1e30+ad))=0
        if (ok) {
            if (n & 1) ado[gr * 8 + h] = av;
            else       aso[gr * 8 + h] = av;
        }
        #pragma unroll
        for (int ct = 0; ct < 8; ++ct) {
            float ot = __shfl_xor(acc[ct][reg], 1);
            if (!(n & 1) && ok)
                h1o[(size_t)gr * 64 + ct * 8 + (n >> 1)] = cvtpk(acc[ct][reg], ot);  // dummy row = 0
        }
    }
}

// ---------------- phase B: CSR build fully in LDS, coalesced dwordx4 flush ----------------
// 1024 threads: this is a 256-block (1 block/CU) kernel -> needs deep per-block wave
// parallelism to hide the load -> LDS-atomic -> flush chain.
__launch_bounds__(1024)
__global__ void k_build(const int* __restrict__ gcur, const u32* __restrict__ bucket,
                        int* __restrict__ cursor, u16* __restrict__ col) {
    __shared__ int cnt[391];
    __shared__ __align__(16) u16 scol[391 * SLOT];   // 50048 B
    int t = threadIdx.x;
    int c = blockIdx.x & (NCLS - 1);
    int g = blockIdx.x >> 7;
    int d0 = cls_base(c);
    int d1 = (c == NCLS - 1) ? N_NODES : cls_base(c + 1);
    int nn = d1 - d0;
    for (int j = t; j < nn; j += 1024) cnt[j] = 0;
    __syncthreads();

    int size = gcur[(g * NCLS + c) * GPAD];
    const u32* bp = bucket + (size_t)(g * NCLS + c) * CAP;
    for (int i = t; i < size; i += 1024) {
        u32 e = bp[i];
        int d = (int)(e >> 16);
        int s = (int)(e & 0xFFFFu);
        int p = atomicAdd(&cnt[d - d0], 1);
        if (p < SLOT) scol[(d - d0) * SLOT + p] = (u16)s;
    }
    __syncthreads();
    int* cur = cursor + g * N_NODES;
    for (int j = t; j < nn; j += 1024) {
        int raw = cnt[j];
        int n0 = min(raw, SLOT);
        int n1 = (n0 + 7) & ~7;            // pad to next multiple of 8 with dummy node
        for (int p = n0; p < n1; ++p) scol[j * SLOT + p] = (u16)N_NODES;
        cur[d0 + j] = raw;
    }
    __syncthreads();
    // coalesced flush: nn*8 uint4 (slots beyond pad carry unread garbage, same as before)
    uint4* dst = (uint4*)(col + ((size_t)g * N_NODES + d0) * SLOT);
    const uint4* srcv = (const uint4*)scol;
    int n16 = nn * 8;
    for (int i = t; i < n16; i += 1024) dst[i] = srcv[i];
}

// ---- k_gat1 pipeline macros: issue gathers for one 8-edge batch / consume it ----
#define GAT1_ISSUE(I, q0,q1,q2,q3,q4,q5,q6,q7, A) do { \
    u32 ix_=(I).x, iy_=(I).y, iz_=(I).z, iw_=(I).w; \
    q0 = *(const u32*)(h1c + (((ix_ & 0xFFFFu) << 8) | lane4)); \
    q1 = *(const u32*)(h1c + (((ix_ >> 16)     << 8) | lane4)); \
    q2 = *(const u32*)(h1c + (((iy_ & 0xFFFFu) << 8) | lane4)); \
    q3 = *(const u32*)(h1c + (((iy_ >> 16)     << 8) | lane4)); \
    q4 = *(const u32*)(h1c + (((iz_ & 0xFFFFu) << 8) | lane4)); \
    q5 = *(const u32*)(h1c + (((iz_ >> 16)     << 8) | lane4)); \
    q6 = *(const u32*)(h1c + (((iw_ & 0xFFFFu) << 8) | lane4)); \
    q7 = *(const u32*)(h1c + (((iw_ >> 16)     << 8) | lane4)); \
    u32 ds_ = (j8 & 4) ? ((j8 & 2) ? iw_ : iz_) : ((j8 & 2) ? iy_ : ix_); \
    u32 sA_ = (j8 & 1) ? (ds_ >> 16) : (ds_ & 0xFFFFu); \
    A = *(const float*)(asc + ((sA_ << 5) | ha4)); \
} while (0)

#define GAT1_CONS(q0,q1,q2,q3,q4,q5,q6,q7, A) do { \
    int wli_ = __float_as_int(__expf(lrelu((A) + ad_a))); \
    float w0 = __int_as_float(__builtin_amdgcn_ds_bpermute(vb,       wli_)); \
    float w1 = __int_as_float(__builtin_amdgcn_ds_bpermute(vb + 32,  wli_)); \
    float w2 = __int_as_float(__builtin_amdgcn_ds_bpermute(vb + 64,  wli_)); \
    float w3 = __int_as_float(__builtin_amdgcn_ds_bpermute(vb + 96,  wli_)); \
    float w4 = __int_as_float(__builtin_amdgcn_ds_bpermute(vb + 128, wli_)); \
    float w5 = __int_as_float(__builtin_amdgcn_ds_bpermute(vb + 160, wli_)); \
    float w6 = __int_as_float(__builtin_amdgcn_ds_bpermute(vb + 192, wli_)); \
    float w7 = __int_as_float(__builtin_amdgcn_ds_bpermute(vb + 224, wli_)); \
    denom += ((w0 + w1) + (w2 + w3)) + ((w4 + w5) + (w6 + w7)); \
    ax += w0 * bflo(q0) + w1 * bflo(q1) + w2 * bflo(q2) + w3 * bflo(q3) \
        + w4 * bflo(q4) + w5 * bflo(q5) + w6 * bflo(q6) + w7 * bflo(q7); \
    ay += w0 * bfhi(q0) + w1 * bfhi(q1) + w2 * bfhi(q2) + w3 * bfhi(q3) \
        + w4 * bfhi(q4) + w5 * bfhi(q5) + w6 * bfhi(q6) + w7 * bfhi(q7); \
} while (0)

// ---------------- GAT layer 1 gather: one wave per node, both graphs (CONTROL: unchanged) ----
__launch_bounds__(256)
__global__ void k_gat1(const u32* __restrict__ h1b, const float* __restrict__ as_,
                       const float* __restrict__ ad_, const int* __restrict__ cursor,
                       const u16* __restrict__ col, const float* __restrict__ b1,
                       u32* __restrict__ hL1) {
    int t = threadIdx.x;
    int lane = t & 63;
    int bid = blockIdx.x;
    int g = bid >= NB_GAT1;
    if (g) bid -= NB_GAT1;
    int node = bid * 4 + (t >> 6);         // grid exact: 12500*4 == N_NODES

    const char*  h1c = (const char*)(h1b + (size_t)g * H1B_ST);
    const char*  asc = (const char*)(as_ + (size_t)g * AS_ST);
    const float* ad1 = ad_ + (size_t)g * AS_ST;
    const u16*   cp  = col + ((size_t)g * N_NODES + node) * SLOT;

    int hc = lane >> 3;                    // channel head (lane covers ch 2L,2L+1)
    int ha = lane & 7;                     // alpha-duty head
    int j8 = lane >> 3;                    // alpha-duty edge-in-batch
    int vb = hc << 2;                      // bpermute byte base: src lane j*8+hc
    u32 lane4 = (u32)lane << 2;
    u32 ha4 = (u32)ha << 2;

    float ad_a = ad1[node * 8 + ha];
    float as_c = as_[(size_t)g * AS_ST + node * 8 + hc];
    float ad_c = ad1[node * 8 + hc];

    // self loop
    float w = __expf(lrelu(as_c + ad_c));
    float denom = w;
    u32 q = *(const u32*)(h1c + (((u32)node << 8) | lane4));
    float ax = w * bflo(q), ay = w * bfhi(q);

    int deg = min(cursor[g * N_NODES + node], SLOT);
    int nb = (deg + 7) >> 3;               // padded CSR: exactly nb full batches
    if (nb) {
        u32 qa0,qa1,qa2,qa3,qa4,qa5,qa6,qa7;
        u32 qb0,qb1,qb2,qb3,qb4,qb5,qb6,qb7;
        float Aa, Ab;
        uint4 Ia, Ib;
        Ia = *(const uint4*)cp;
        GAT1_ISSUE(Ia, qa0,qa1,qa2,qa3,qa4,qa5,qa6,qa7, Aa);
        if (nb > 1) {
            Ib = *(const uint4*)(cp + 8);
            GAT1_ISSUE(Ib, qb0,qb1,qb2,qb3,qb4,qb5,qb6,qb7, Ab);
        }
        int b = 0;
        for (;;) {
            GAT1_CONS(qa0,qa1,qa2,qa3,qa4,qa5,qa6,qa7, Aa);
            if (++b >= nb) break;
            if (b + 1 < nb) {
                Ia = *(const uint4*)(cp + (b + 1) * 8);
                GAT1_ISSUE(Ia, qa0,qa1,qa2,qa3,qa4,qa5,qa6,qa7, Aa);
            }
            GAT1_CONS(qb0,qb1,qb2,qb3,qb4,qb5,qb6,qb7, Ab);
            if (++b >= nb) break;
            if (b + 1 < nb) {
                Ib = *(const uint4*)(cp + (b + 1) * 8);
                GAT1_ISSUE(Ib, qb0,qb1,qb2,qb3,qb4,qb5,qb6,qb7, Ab);
            }
        }
    }
    float inv = 1.f / (denom + 1e-16f);
    int c = lane * 2;
    float o0 = ax * inv + b1[c];
    float o1 = ay * inv + b1[c + 1];
    o0 = (o0 > 0.f) ? o0 : (__expf(o0) - 1.f);   // ELU
    o1 = (o1 > 0.f) ? o1 : (__expf(o1) - 1.f);
    hL1[(size_t)g * HL1_ST + (size_t)node * 64 + lane] = cvtpk(o0, o1);
}

// ---------------- GEMM2 (+fused alpha2), both graphs, writes dummy row ----------------
__launch_bounds__(256)
__global__ void k_gemm2(const u32* __restrict__ hL1, const float* __restrict__ W2,
                        const float* __restrict__ a2s, const float* __restrict__ a2d,
                        float* __restrict__ h2, float* __restrict__ as2,
                        float* __restrict__ ad2) {
    __shared__ float w2s[F_INS * C_OUT];  // 8 KB, [k][c]
    __shared__ float hs[16 * 136];        // padded stride 136
    int t = threadIdx.x;
    int bid = blockIdx.x;
    int g = bid >= NB_G2;
    if (g) bid -= NB_G2;
    const u16* hL = (const u16*)(hL1 + (size_t)g * HL1_ST);
    float* h2o  = h2  + (size_t)g * H2_ST;
    float* as2o = as2 + (size_t)g * AS2_ST;
    float* ad2o = ad2 + (size_t)g * AS2_ST;

    const float4* w4 = (const float4*)W2;     // 512 float4s
    #pragma unroll
    for (int i = 0; i < 2; ++i) {
        int idx = t + i * 256;
        ((float4*)w2s)[idx] = w4[idx];
    }
    int r0 = bid * 16;
    const ushort4* hg = (const ushort4*)hL;   // 32 ushort4 per row
    #pragma unroll
    for (int i = 0; i < 2; ++i) {
        int idx = t + i * 256;      // 0..511
        int r  = idx >> 5;          // 0..15
        int c4 = idx & 31;
        ushort4 qq = make_ushort4(0, 0, 0, 0);
        if (r0 + r < N_NODES) qq = hg[(size_t)(r0 + r) * 32 + c4];
        float4 v; v.x = bf2f(qq.x); v.y = bf2f(qq.y); v.z = bf2f(qq.z); v.w = bf2f(qq.w);
        *(float4*)(hs + r * 136 + c4 * 4) = v;
    }
    __syncthreads();

    int c = t & 15, r = t >> 4;
    float acc = 0.f;
    #pragma unroll 8
    for (int k = 0; k < F_INS; ++k) acc += hs[r * 136 + k] * w2s[k * C_OUT + c];
    int n = r0 + r;
    if (n <= N_NODES) h2o[(size_t)n * C_OUT + c] = acc;   // dummy row: acc==0

    // fused alpha2: 16-lane butterfly within each row group
    float sa = acc * a2s[c];
    float sd = acc * a2d[c];
    #pragma unroll
    for (int m = 1; m < 16; m <<= 1) {
        sa += __shfl_xor(sa, m);
        sd += __shfl_xor(sd, m);
    }
    if (c == 0 && n <= N_NODES) {
        as2o[n] = (n == N_NODES) ? -1e30f : sa;           // dummy: w=0
        ad2o[n] = sd;
    }
}

// ---- k_gat2 pipeline macros (parameterized by stream) ----
#define G2_ISSUE(I, H2C, ASC, v0,v1,v2,v3,v4,v5,v6,v7, A) do { \
    u32 ix_=(I).x, iy_=(I).y, iz_=(I).z, iw_=(I).w; \
    v0 = *(const float*)((H2C) + (((ix_ & 0xFFFFu) << 6) | c4)); \
    v1 = *(const float*)((H2C) + (((ix_ >> 16)     << 6) | c4)); \
    v2 = *(const float*)((H2C) + (((iy_ & 0xFFFFu) << 6) | c4)); \
    v3 = *(const float*)((H2C) + (((iy_ >> 16)     << 6) | c4)); \
    v4 = *(const float*)((H2C) + (((iz_ & 0xFFFFu) << 6) | c4)); \
    v5 = *(const float*)((H2C) + (((iz_ >> 16)     << 6) | c4)); \
    v6 = *(const float*)((H2C) + (((iw_ & 0xFFFFu) << 6) | c4)); \
    v7 = *(const float*)((H2C) + (((iw_ >> 16)     << 6) | c4)); \
    u32 ds_ = (jsel & 4) ? ((jsel & 2) ? iw_ : iz_) : ((jsel & 2) ? iy_ : ix_); \
    u32 sA_ = (jsel & 1) ? (ds_ >> 16) : (ds_ & 0xFFFFu); \
    A = *(const float*)((ASC) + (sA_ << 2)); \
} while (0)

#define G2_CONS(v0,v1,v2,v3,v4,v5,v6,v7, A, AD, DEN, ACC) do { \
    int wli_ = __float_as_int(__expf(lrelu((A) + (AD)))); \
    float w0 = __int_as_float(__builtin_amdgcn_ds_bpermute(gb,      wli_)); \
    float w1 = __int_as_float(__builtin_amdgcn_ds_bpermute(gb + 4,  wli_)); \
    float w2 = __int_as_float(__builtin_amdgcn_ds_bpermute(gb + 8,  wli_)); \
    float w3 = __int_as_float(__builtin_amdgcn_ds_bpermute(gb + 12, wli_)); \
    float w4 = __int_as_float(__builtin_amdgcn_ds_bpermute(gb + 16, wli_)); \
    float w5 = __int_as_float(__builtin_amdgcn_ds_bpermute(gb + 20, wli_)); \
    float w6 = __int_as_float(__builtin_amdgcn_ds_bpermute(gb + 24, wli_)); \
    float w7 = __int_as_float(__builtin_amdgcn_ds_bpermute(gb + 28, wli_)); \
    DEN += ((w0 + w1) + (w2 + w3)) + ((w4 + w5) + (w6 + w7)); \
    ACC += (w0 * v0 + w1 * v1 + w2 * v2 + w3 * v3) \
         + (w4 * v4 + w5 * v5 + w6 * v6 + w7 * v7); \
} while (0)

// ---------------- GAT layer 2 both graphs + fused epilogue ----------------
__launch_bounds__(256)
__global__ void k_gat2e(const float* __restrict__ h2, const float* __restrict__ as2,
                        const float* __restrict__ ad2, const int* __restrict__ cursor,
                        const u16* __restrict__ col, const float* __restrict__ b2,
                        float* __restrict__ out) {
    int t = threadIdx.x;
    int node = blockIdx.x * 16 + (t >> 4);   // grid exact: 3125*16 == N_NODES
    int c = t & 15;
    int lane = t & 63;
    u32 c4 = (u32)c << 2;
    int jsel = lane & 7;
    u32 gb = (u32)(lane & 48) << 2;          // bpermute group base byte
    float b2c = b2[c];

    const char* h2Y = (const char*)h2;
    const char* h2Z = (const char*)(h2 + H2_ST);
    const char* asY = (const char*)as2;
    const char* asZ = (const char*)(as2 + AS2_ST);
    const u16* cpY = col + (size_t)node * SLOT;
    const u16* cpZ = col + ((size_t)N_NODES + node) * SLOT;
    float adY = ad2[node];
    float adZ = ad2[AS2_ST + node];

    // self loops
    float wY = __expf(lrelu(*(const float*)(asY + ((u32)node << 2)) + adY));
    float dY = wY;
    float aY = wY * *(const float*)(h2Y + (((u32)node << 6) | c4));
    float wZ = __expf(lrelu(*(const float*)(asZ + ((u32)node << 2)) + adZ));
    float dZ = wZ;
    float aZ = wZ * *(const float*)(h2Z + (((u32)node << 6) | c4));

    int nbY = (min(cursor[node], SLOT) + 7) >> 3;
    int nbZ = (min(cursor[N_NODES + node], SLOT) + 7) >> 3;

    float y0,y1,y2,y3,y4,y5,y6,y7, Ay;
    float z0,z1,z2,z3,z4,z5,z6,z7, Az;
    uint4 I;
    if (nbY) { I = *(const uint4*)cpY; G2_ISSUE(I, h2Y, asY, y0,y1,y2,y3,y4,y5,y6,y7, Ay); }
    if (nbZ) { I = *(const uint4*)cpZ; G2_ISSUE(I, h2Z, asZ, z0,z1,z2,z3,z4,z5,z6,z7, Az); }
    int bY = 0, bZ = 0;
    while (bY < nbY || bZ < nbZ) {
        if (bY < nbY) {
            G2_CONS(y0,y1,y2,y3,y4,y5,y6,y7, Ay, adY, dY, aY);
            ++bY;
            if (bY < nbY) {
                I = *(const uint4*)(cpY + bY * 8);
                G2_ISSUE(I, h2Y, asY, y0,y1,y2,y3,y4,y5,y6,y7, Ay);
            }
        }
        if (bZ < nbZ) {
            G2_CONS(z0,z1,z2,z3,z4,z5,z6,z7, Az, adZ, dZ, aZ);
            ++bZ;
            if (bZ < nbZ) {
                I = *(const uint4*)(cpZ + bZ * 8);
                G2_ISSUE(I, h2Z, asZ, z0,z1,z2,z3,z4,z5,z6,z7, Az);
            }
        }
    }
    float yv = aY / (dY + 1e-16f) + b2c;
    float zv = aZ / (dZ + 1e-16f) + b2c;

    float my = yv, mz = zv;
    #pragma unroll
    for (int m = 1; m < 16; m <<= 1) {
        my = fmaxf(my, __shfl_xor(my, m));
        mz = fmaxf(mz, __shfl_xor(mz, m));
    }
    float sy = __expf(yv - my), sz = __expf(zv - mz);
    float dot = yv * zv, ny = yv * yv, nz = zv * zv;
    #pragma unroll
    for (int m = 1; m < 16; m <<= 1) {
        sy  += __shfl_xor(sy, m);
        sz  += __shfl_xor(sz, m);
        dot += __shfl_xor(dot, m);
        ny  += __shfl_xor(ny, m);
        nz  += __shfl_xor(nz, m);
    }
    float lsey = my + __logf(sy);
    float lsez = mz + __logf(sz);
    float omc = 1.f - dot / (fmaxf(sqrtf(ny), 1e-8f) * fmaxf(sqrtf(nz), 1e-8f));

    const int O1 = N_NODES * C_OUT;            //  800000: 1-cos
    const int O2 = O1 + N_NODES;               //  850000: ls_z
    const int O3 = O2 + N_NODES * C_OUT;       // 1650000: ls_y
    const int O4 = O3 + N_NODES * C_OUT;       // 2450000: ls_y
    float ly = yv - lsey;
    float lz = zv - lsez;
    int base = node * 16 + c;
    out[base]      = ly;
    out[O2 + base] = lz;
    out[O3 + base] = ly;
    out[O4 + base] = ly;
    if (c == 0) out[O1 + node] = omc;
}

extern "C" void kernel_launch(void* const* d_in, const int* in_sizes, int n_in,
                              void* d_out, int out_size, void* d_ws, size_t ws_size,
                              hipStream_t stream) {
    (void)in_sizes; (void)n_in; (void)out_size; (void)ws_size;
    const float* x1  = (const float*)d_in[0];
    const int*   ei1 = (const int*)d_in[1];
    const float* x2  = (const float*)d_in[2];
    const int*   ei2 = (const int*)d_in[3];
    const float* W1  = (const float*)d_in[4];
    const float* a1s = (const float*)d_in[5];
    const float* a1d = (const float*)d_in[6];
    const float* b1  = (const float*)d_in[7];
    const float* W2  = (const float*)d_in[8];
    const float* a2s = (const float*)d_in[9];
    const float* a2d = (const float*)d_in[10];
    const float* b2  = (const float*)d_in[11];
    float* out = (float*)d_out;

    // Workspace layout: ~78 MB. bucket (8 MB) aliases hL1 (25.6 MB): bucket is
    // consumed by k_build (L3) before k_gat1 (L4) first writes hL1.
    char* p = (char*)d_ws;
    int* gcur      = (int*)p; p += (size_t)2 * NCLS * GPAD * 4;      //  16 KB (line-padded)
    u32* w1t       = (u32*)p; p += (size_t)128 * 64 * 4;             //  32 KB (bf16 W1T [c][k])
    u32* a1t       = (u32*)p; p += (size_t)16 * 64 * 4;              //   4 KB (bf16 A1T [n][k])
    int* cursor    = (int*)p; p += (size_t)2 * N_NODES * 4;          //   0.4 MB
    u16* col       = (u16*)p; p += (size_t)2 * N_NODES * SLOT * 2;   //  12.8 MB
    float* as1  = (float*)p; p += (size_t)2 * AS_ST * 4;             //   3.2 MB
    float* ad1  = (float*)p; p += (size_t)2 * AS_ST * 4;             //   3.2 MB
    float* h2   = (float*)p; p += (size_t)2 * H2_ST * 4;             //   6.4 MB
    float* as2  = (float*)p; p += (size_t)2 * AS2_ST * 4;            //   0.4 MB
    float* ad2  = (float*)p; p += (size_t)2 * AS2_ST * 4;            //   0.4 MB
    u32* hL1    = (u32*)p;   p += (size_t)2 * HL1_ST * 4;            //  25.6 MB (bf16)
    u32* h1b    = (u32*)p;   p += (size_t)2 * H1B_ST * 4;            //  25.6 MB (bf16)
    u32* bucket = hL1;                                               //   8 MB alias

    k_wt    <<<33, 256, 0, stream>>>(W1, a1s, a1d, w1t, a1t, gcur);
    k_bg1   <<<2 * NB_BKT + 2 * NB_G1, 256, 0, stream>>>(ei1, ei2, gcur, bucket,
                                                         x1, x2, w1t, a1t, h1b, as1, ad1);
    k_build <<<2 * NCLS, 1024, 0, stream>>>(gcur, bucket, cursor, col);
    k_gat1  <<<2 * NB_GAT1, 256, 0, stream>>>(h1b, as1, ad1, cursor, col, b1, hL1);
    k_gemm2 <<<2 * NB_G2, 256, 0, stream>>>(hL1, W2, a2s, a2d, h2, as2, ad2);
    k_gat2e <<<N_NODES / 16, 256, 0, stream>>>(h2, as2, ad2, cursor, col, b2, out);
}

// Round 6
// 291.497 us; speedup vs baseline: 1.1660x; 1.0506x over previous
//
#include <hip/hip_runtime.h>
#include <hip/hip_bf16.h>

#define N_NODES 50000
#define N_EDGES 800000
#define F_INS   128
#define HIDDEN  16
#define HEADS   8
#define HO      128      // HEADS*HIDDEN
#define C_OUT   16
#define NEG_SLOPE 0.2f
#define SLOT    64       // fixed col slots per node; P(Poisson(16) > 64) ~ 1e-20
#define NB_G1   ((N_NODES + 63) / 64)     // 782 blocks for MFMA gemm1 (per graph)
#define NB_GAT1 ((N_NODES + 3) / 4)       // 12500 blocks for gat1 (per graph)
#define NB_G2   ((N_NODES + 16) / 16)     // 3126 blocks for gemm2 (per graph, covers dummy row)

// padded row counts / strides (dummy node index == N_NODES)
#define NP      50016                      // N_NODES rounded up (+dummy row), 16-aligned
#define AS_ST   ((size_t)NP * 8)           // floats per graph for as1/ad1
#define H1B_ST  ((size_t)NP * 64)          // u32 per graph for h1b (bf16 pairs)
#define HL1_ST  ((size_t)N_NODES * 64)     // u32 per graph for hL1
#define H2_ST   ((size_t)NP * 16)          // floats per graph for h2
#define AS2_ST  ((size_t)NP)               // floats per graph for as2/ad2

// ---- two-phase CSR build constants ----
#define NCLS     128                       // node classes; cls = (d*1342)>>19, <=391 nodes/class
#define CLS_MUL  1342u
#define CLS_SH   19
#define CAP      8192                      // bucket capacity per (graph,class); expect ~6256
#define CHUNK    2048                      // edges per bucket block (256 thr x 8)
#define NB_BKT   ((N_EDGES + CHUNK - 1) / CHUNK)   // 391 chunks per graph
#define GPAD     16                        // gcur stride: 1 counter per 64B cache line

typedef unsigned short u16;
typedef unsigned int   u32;
typedef int v4i __attribute__((ext_vector_type(4)));
typedef short bf16x8 __attribute__((ext_vector_type(8)));
typedef float f32x4 __attribute__((ext_vector_type(4)));

__device__ __forceinline__ float bf2f(u16 u) {
    union { u32 i; float f; } t; t.i = ((u32)u) << 16; return t.f;
}
__device__ __forceinline__ float bflo(u32 q) {
    union { u32 i; float f; } t; t.i = q << 16; return t.f;
}
__device__ __forceinline__ float bfhi(u32 q) {
    union { u32 i; float f; } t; t.i = q & 0xFFFF0000u; return t.f;
}
__device__ __forceinline__ u32 f2bf(float f) {
    union { float f; u32 i; } t; t.f = f;
    u32 x = t.i;
    u32 lsb = (x >> 16) & 1u;
    x += 0x7FFFu + lsb;
    return x >> 16;
}
// HW packed f32->bf16 RNE convert (same rounding as f2bf, 1 instr instead of ~10)
__device__ __forceinline__ u32 cvtpk(float lo, float hi) {
    u32 r;
    asm("v_cvt_pk_bf16_f32 %0, %1, %2" : "=v"(r) : "v"(lo), "v"(hi));
    return r;
}
__device__ __forceinline__ float lrelu(float t) {
    return fmaxf(t, NEG_SLOPE * t);   // exact leaky-relu: 0.2t>t iff t<0
}
__device__ __forceinline__ int cls_of(int d) { return (int)(((u32)d * CLS_MUL) >> CLS_SH); }
__host__ __device__ __forceinline__ int cls_base(int c) { return (int)(((u32)c * 524288u + (CLS_MUL - 1)) / CLS_MUL); }

// ---------------- prep: W1T bf16 [c][k] + A1T bf16 [n][k] + gcur zero ----------------
__global__ void k_wt(const float* __restrict__ W1, const float* __restrict__ a1s,
                     const float* __restrict__ a1d, u32* __restrict__ w1t,
                     u32* __restrict__ a1t, int* __restrict__ gcur) {
    int t = threadIdx.x;
    if (blockIdx.x < 32) {
        int e = blockIdx.x * 256 + t;    // 0..8191
        int c = e >> 6, kp = e & 63;
        float lo = W1[(2 * kp) * 128 + c];
        float hi = W1[(2 * kp + 1) * 128 + c];
        w1t[e] = (f2bf(hi) << 16) | f2bf(lo);
    } else {
        #pragma unroll
        for (int i = 0; i < GPAD; ++i) gcur[t * GPAD + i] = 0;   // 2*NCLS*GPAD ints
        #pragma unroll
        for (int i = 0; i < 4; ++i) {
            int wi = t + i * 256;        // 0..1023
            int n = wi >> 6, kp = wi & 63;
            int h = n >> 1;
            const float* av = ((n & 1) ? a1d : a1s) + h * 16;
            float s0 = 0.f, s1 = 0.f;
            #pragma unroll
            for (int c = 0; c < 16; ++c) {
                s0 += W1[(2 * kp) * 128 + h * 16 + c] * av[c];
                s1 += W1[(2 * kp + 1) * 128 + h * 16 + c] * av[c];
            }
            a1t[wi] = (f2bf(s1) << 16) | f2bf(s0);
        }
    }
}

// ---------------- FAT: edge bucketing (blocks 0..781) + GEMM1 (blocks 782..2345) ----
// GEMM1 (r6 bisection): A-fragments direct global->reg (each lane's fragment = 8
// contiguous floats of its row -- bit-identical values to the old LDS staging);
// B-fragments via round-4's EXACT global reads (proven numerics; r5's swizzled-LDS
// B-path reverted as the suspected source of the replay-instability failure).
// No LDS / no barrier in the gemm1 body -> staging drain removed, occupancy up.
__launch_bounds__(256)
__global__ void k_bg1(const int* __restrict__ ei0, const int* __restrict__ ei1,
                      int* __restrict__ gcur, u32* __restrict__ bucket,
                      const float* __restrict__ x1g, const float* __restrict__ x2g,
                      const u32* __restrict__ w1t, const u32* __restrict__ a1t,
                      u32* __restrict__ h1b, float* __restrict__ as_,
                      float* __restrict__ ad_) {
    __shared__ int cnt[NCLS];   // 1 KB (bucket)
    __shared__ int bse[NCLS];
    int t = threadIdx.x;

    if (blockIdx.x < 2 * NB_BKT) {
        // ---------------- bucket body ----------------
        int g = blockIdx.x & 1;
        int chunk = blockIdx.x >> 1;
        int e0 = chunk * CHUNK + t * 8;
        bool act = e0 < N_EDGES;

        if (t < NCLS) cnt[t] = 0;
        __syncthreads();

        const int* src = g ? ei1 : ei0;
        const int* dst = src + N_EDGES;
        int d8[8], s8[8], c8[8];
        if (act) {
            v4i da = *(const v4i*)(dst + e0), db = *(const v4i*)(dst + e0 + 4);
            v4i sa = *(const v4i*)(src + e0), sb = *(const v4i*)(src + e0 + 4);
            d8[0]=da[0]; d8[1]=da[1]; d8[2]=da[2]; d8[3]=da[3];
            d8[4]=db[0]; d8[5]=db[1]; d8[6]=db[2]; d8[7]=db[3];
            s8[0]=sa[0]; s8[1]=sa[1]; s8[2]=sa[2]; s8[3]=sa[3];
            s8[4]=sb[0]; s8[5]=sb[1]; s8[6]=sb[2]; s8[7]=sb[3];
            #pragma unroll
            for (int j = 0; j < 8; ++j) {
                c8[j] = cls_of(d8[j]);
                atomicAdd(&cnt[c8[j]], 1);
            }
        }
        __syncthreads();
        if (t < NCLS) {
            int n = cnt[t];
            bse[t] = n ? atomicAdd(&gcur[(g * NCLS + t) * GPAD], n) : 0;
            cnt[t] = 0;
        }
        __syncthreads();
        if (act) {
            #pragma unroll
            for (int j = 0; j < 8; ++j) {
                int c = c8[j];
                int p = atomicAdd(&cnt[c], 1);
                bucket[(size_t)(g * NCLS + c) * CAP + bse[c] + p] =
                    ((u32)d8[j] << 16) | (u32)s8[j];
            }
        }
        return;
    }

    // ---------------- gemm1 body ----------------
    int bid = blockIdx.x - 2 * NB_BKT;
    int g = bid >= NB_G1;
    if (g) bid -= NB_G1;
    const float* x = g ? x2g : x1g;
    u32*   h1o = h1b + (size_t)g * H1B_ST;
    float* aso = as_ + (size_t)g * AS_ST;
    float* ado = ad_ + (size_t)g * AS_ST;
    int r0 = bid * 64;

    int lane = t & 63;
    int wid = t >> 6;
    int n = lane & 15, quad = lane >> 4;

    // A-fragments direct: row r = r0+wid*16+n, cols kt*32+quad*8+{0..7}
    // (exact mapping of the old staged layout; OOB rows -> 0, same as staged zeros)
    int r = r0 + wid * 16 + n;
    bool rok = r < N_NODES;
    const float4* xr = (const float4*)(x + (size_t)r * 128);
    float4 xf[8];
    #pragma unroll
    for (int kt = 0; kt < 4; ++kt) {
        int cb = kt * 8 + quad * 2;         // float4 index of col kt*32+quad*8
        xf[kt * 2]     = rok ? xr[cb]     : make_float4(0.f, 0.f, 0.f, 0.f);
        xf[kt * 2 + 1] = rok ? xr[cb + 1] : make_float4(0.f, 0.f, 0.f, 0.f);
    }

    f32x4 acc[8], acca;
    #pragma unroll
    for (int ct = 0; ct < 8; ++ct) acc[ct] = (f32x4){0.f, 0.f, 0.f, 0.f};
    acca = (f32x4){0.f, 0.f, 0.f, 0.f};

    #pragma unroll
    for (int kt = 0; kt < 4; ++kt) {
        union { uint4 u; bf16x8 v; } af;
        float4 f0 = xf[kt * 2], f1 = xf[kt * 2 + 1];
        af.u.x = cvtpk(f0.x, f0.y);
        af.u.y = cvtpk(f0.z, f0.w);
        af.u.z = cvtpk(f1.x, f1.y);
        af.u.w = cvtpk(f1.z, f1.w);
        #pragma unroll
        for (int ct = 0; ct < 8; ++ct) {
            union { uint4 u; bf16x8 v; } bf_;
            bf_.u = *(const uint4*)(w1t + (ct * 16 + n) * 64 + kt * 16 + quad * 4);
            acc[ct] = __builtin_amdgcn_mfma_f32_16x16x32_bf16(af.v, bf_.v, acc[ct], 0, 0, 0);
        }
        union { uint4 u; bf16x8 v; } ba;
        ba.u = *(const uint4*)(a1t + n * 64 + kt * 16 + quad * 4);
        acca = __builtin_amdgcn_mfma_f32_16x16x32_bf16(af.v, ba.v, acca, 0, 0, 0);
    }

    // C/D layout: col = lane&15, row = quad*4+reg [m89]
    int h = n >> 1;
    #pragma unroll
    for (int reg = 0; reg < 4; ++reg) {
        int gr = r0 + wid * 16 + quad * 4 + reg;
        bool ok = gr <= N_NODES;           // include dummy row
        float av = (gr == N_NODES) ? -1e30f : acca[reg];  // dummy: w=exp(leaky(-1e30+ad))=0
        if (ok) {
            if (n & 1) ado[gr * 8 + h] = av;
            else       aso[gr * 8 + h] = av;
        }
        #pragma unroll
        for (int ct = 0; ct < 8; ++ct) {
            float ot = __shfl_xor(acc[ct][reg], 1);
            if (!(n & 1) && ok)
                h1o[(size_t)gr * 64 + ct * 8 + (n >> 1)] = cvtpk(acc[ct][reg], ot);  // dummy row = 0
        }
    }
}

// ---------------- phase B: CSR build fully in LDS, coalesced dwordx4 flush ----------------
__launch_bounds__(1024)
__global__ void k_build(const int* __restrict__ gcur, const u32* __restrict__ bucket,
                        int* __restrict__ cursor, u16* __restrict__ col) {
    __shared__ int cnt[391];
    __shared__ __align__(16) u16 scol[391 * SLOT];   // 50048 B
    int t = threadIdx.x;
    int c = blockIdx.x & (NCLS - 1);
    int g = blockIdx.x >> 7;
    int d0 = cls_base(c);
    int d1 = (c == NCLS - 1) ? N_NODES : cls_base(c + 1);
    int nn = d1 - d0;
    for (int j = t; j < nn; j += 1024) cnt[j] = 0;
    __syncthreads();

    int size = gcur[(g * NCLS + c) * GPAD];
    const u32* bp = bucket + (size_t)(g * NCLS + c) * CAP;
    for (int i = t; i < size; i += 1024) {
        u32 e = bp[i];
        int d = (int)(e >> 16);
        int s = (int)(e & 0xFFFFu);
        int p = atomicAdd(&cnt[d - d0], 1);
        if (p < SLOT) scol[(d - d0) * SLOT + p] = (u16)s;
    }
    __syncthreads();
    int* cur = cursor + g * N_NODES;
    for (int j = t; j < nn; j += 1024) {
        int raw = cnt[j];
        int n0 = min(raw, SLOT);
        int n1 = (n0 + 7) & ~7;            // pad to next multiple of 8 with dummy node
        for (int p = n0; p < n1; ++p) scol[j * SLOT + p] = (u16)N_NODES;
        cur[d0 + j] = raw;
    }
    __syncthreads();
    // coalesced flush: nn*8 uint4 (slots beyond pad carry unread garbage, same as before)
    uint4* dst = (uint4*)(col + ((size_t)g * N_NODES + d0) * SLOT);
    const uint4* srcv = (const uint4*)scol;
    int n16 = nn * 8;
    for (int i = t; i < n16; i += 1024) dst[i] = srcv[i];
}

// ---- k_gat1 pipeline macros: issue gathers for one 8-edge batch / consume it ----
#define GAT1_ISSUE(I, q0,q1,q2,q3,q4,q5,q6,q7, A) do { \
    u32 ix_=(I).x, iy_=(I).y, iz_=(I).z, iw_=(I).w; \
    q0 = *(const u32*)(h1c + (((ix_ & 0xFFFFu) << 8) | lane4)); \
    q1 = *(const u32*)(h1c + (((ix_ >> 16)     << 8) | lane4)); \
    q2 = *(const u32*)(h1c + (((iy_ & 0xFFFFu) << 8) | lane4)); \
    q3 = *(const u32*)(h1c + (((iy_ >> 16)     << 8) | lane4)); \
    q4 = *(const u32*)(h1c + (((iz_ & 0xFFFFu) << 8) | lane4)); \
    q5 = *(const u32*)(h1c + (((iz_ >> 16)     << 8) | lane4)); \
    q6 = *(const u32*)(h1c + (((iw_ & 0xFFFFu) << 8) | lane4)); \
    q7 = *(const u32*)(h1c + (((iw_ >> 16)     << 8) | lane4)); \
    u32 ds_ = (j8 & 4) ? ((j8 & 2) ? iw_ : iz_) : ((j8 & 2) ? iy_ : ix_); \
    u32 sA_ = (j8 & 1) ? (ds_ >> 16) : (ds_ & 0xFFFFu); \
    A = *(const float*)(asc + ((sA_ << 5) | ha4)); \
} while (0)

#define GAT1_CONS(q0,q1,q2,q3,q4,q5,q6,q7, A) do { \
    int wli_ = __float_as_int(__expf(lrelu((A) + ad_a))); \
    float w0 = __int_as_float(__builtin_amdgcn_ds_bpermute(vb,       wli_)); \
    float w1 = __int_as_float(__builtin_amdgcn_ds_bpermute(vb + 32,  wli_)); \
    float w2 = __int_as_float(__builtin_amdgcn_ds_bpermute(vb + 64,  wli_)); \
    float w3 = __int_as_float(__builtin_amdgcn_ds_bpermute(vb + 96,  wli_)); \
    float w4 = __int_as_float(__builtin_amdgcn_ds_bpermute(vb + 128, wli_)); \
    float w5 = __int_as_float(__builtin_amdgcn_ds_bpermute(vb + 160, wli_)); \
    float w6 = __int_as_float(__builtin_amdgcn_ds_bpermute(vb + 192, wli_)); \
    float w7 = __int_as_float(__builtin_amdgcn_ds_bpermute(vb + 224, wli_)); \
    denom += ((w0 + w1) + (w2 + w3)) + ((w4 + w5) + (w6 + w7)); \
    ax += w0 * bflo(q0) + w1 * bflo(q1) + w2 * bflo(q2) + w3 * bflo(q3) \
        + w4 * bflo(q4) + w5 * bflo(q5) + w6 * bflo(q6) + w7 * bflo(q7); \
    ay += w0 * bfhi(q0) + w1 * bfhi(q1) + w2 * bfhi(q2) + w3 * bfhi(q3) \
        + w4 * bfhi(q4) + w5 * bfhi(q5) + w6 * bfhi(q6) + w7 * bfhi(q7); \
} while (0)

// ---------------- GAT layer 1 gather: one wave per node, both graphs (CONTROL: unchanged) ----
__launch_bounds__(256)
__global__ void k_gat1(const u32* __restrict__ h1b, const float* __restrict__ as_,
                       const float* __restrict__ ad_, const int* __restrict__ cursor,
                       const u16* __restrict__ col, const float* __restrict__ b1,
                       u32* __restrict__ hL1) {
    int t = threadIdx.x;
    int lane = t & 63;
    int bid = blockIdx.x;
    int g = bid >= NB_GAT1;
    if (g) bid -= NB_GAT1;
    int node = bid * 4 + (t >> 6);         // grid exact: 12500*4 == N_NODES

    const char*  h1c = (const char*)(h1b + (size_t)g * H1B_ST);
    const char*  asc = (const char*)(as_ + (size_t)g * AS_ST);
    const float* ad1 = ad_ + (size_t)g * AS_ST;
    const u16*   cp  = col + ((size_t)g * N_NODES + node) * SLOT;

    int hc = lane >> 3;                    // channel head (lane covers ch 2L,2L+1)
    int ha = lane & 7;                     // alpha-duty head
    int j8 = lane >> 3;                    // alpha-duty edge-in-batch
    int vb = hc << 2;                      // bpermute byte base: src lane j*8+hc
    u32 lane4 = (u32)lane << 2;
    u32 ha4 = (u32)ha << 2;

    float ad_a = ad1[node * 8 + ha];
    float as_c = as_[(size_t)g * AS_ST + node * 8 + hc];
    float ad_c = ad1[node * 8 + hc];

    // self loop
    float w = __expf(lrelu(as_c + ad_c));
    float denom = w;
    u32 q = *(const u32*)(h1c + (((u32)node << 8) | lane4));
    float ax = w * bflo(q), ay = w * bfhi(q);

    int deg = min(cursor[g * N_NODES + node], SLOT);
    int nb = (deg + 7) >> 3;               // padded CSR: exactly nb full batches
    if (nb) {
        u32 qa0,qa1,qa2,qa3,qa4,qa5,qa6,qa7;
        u32 qb0,qb1,qb2,qb3,qb4,qb5,qb6,qb7;
        float Aa, Ab;
        uint4 Ia, Ib;
        Ia = *(const uint4*)cp;
        GAT1_ISSUE(Ia, qa0,qa1,qa2,qa3,qa4,qa5,qa6,qa7, Aa);
        if (nb > 1) {
            Ib = *(const uint4*)(cp + 8);
            GAT1_ISSUE(Ib, qb0,qb1,qb2,qb3,qb4,qb5,qb6,qb7, Ab);
        }
        int b = 0;
        for (;;) {
            GAT1_CONS(qa0,qa1,qa2,qa3,qa4,qa5,qa6,qa7, Aa);
            if (++b >= nb) break;
            if (b + 1 < nb) {
                Ia = *(const uint4*)(cp + (b + 1) * 8);
                GAT1_ISSUE(Ia, qa0,qa1,qa2,qa3,qa4,qa5,qa6,qa7, Aa);
            }
            GAT1_CONS(qb0,qb1,qb2,qb3,qb4,qb5,qb6,qb7, Ab);
            if (++b >= nb) break;
            if (b + 1 < nb) {
                Ib = *(const uint4*)(cp + (b + 1) * 8);
                GAT1_ISSUE(Ib, qb0,qb1,qb2,qb3,qb4,qb5,qb6,qb7, Ab);
            }
        }
    }
    float inv = 1.f / (denom + 1e-16f);
    int c = lane * 2;
    float o0 = ax * inv + b1[c];
    float o1 = ay * inv + b1[c + 1];
    o0 = (o0 > 0.f) ? o0 : (__expf(o0) - 1.f);   // ELU
    o1 = (o1 > 0.f) ? o1 : (__expf(o1) - 1.f);
    hL1[(size_t)g * HL1_ST + (size_t)node * 64 + lane] = cvtpk(o0, o1);
}

// ---------------- GEMM2 (+fused alpha2), both graphs, writes dummy row ----------------
__launch_bounds__(256)
__global__ void k_gemm2(const u32* __restrict__ hL1, const float* __restrict__ W2,
                        const float* __restrict__ a2s, const float* __restrict__ a2d,
                        float* __restrict__ h2, float* __restrict__ as2,
                        float* __restrict__ ad2) {
    __shared__ float w2s[F_INS * C_OUT];  // 8 KB, [k][c]
    __shared__ float hs[16 * 136];        // padded stride 136
    int t = threadIdx.x;
    int bid = blockIdx.x;
    int g = bid >= NB_G2;
    if (g) bid -= NB_G2;
    const u16* hL = (const u16*)(hL1 + (size_t)g * HL1_ST);
    float* h2o  = h2  + (size_t)g * H2_ST;
    float* as2o = as2 + (size_t)g * AS2_ST;
    float* ad2o = ad2 + (size_t)g * AS2_ST;

    const float4* w4 = (const float4*)W2;     // 512 float4s
    #pragma unroll
    for (int i = 0; i < 2; ++i) {
        int idx = t + i * 256;
        ((float4*)w2s)[idx] = w4[idx];
    }
    int r0 = bid * 16;
    const ushort4* hg = (const ushort4*)hL;   // 32 ushort4 per row
    #pragma unroll
    for (int i = 0; i < 2; ++i) {
        int idx = t + i * 256;      // 0..511
        int r  = idx >> 5;          // 0..15
        int c4 = idx & 31;
        ushort4 qq = make_ushort4(0, 0, 0, 0);
        if (r0 + r < N_NODES) qq = hg[(size_t)(r0 + r) * 32 + c4];
        float4 v; v.x = bf2f(qq.x); v.y = bf2f(qq.y); v.z = bf2f(qq.z); v.w = bf2f(qq.w);
        *(float4*)(hs + r * 136 + c4 * 4) = v;
    }
    __syncthreads();

    int c = t & 15, r = t >> 4;
    float acc = 0.f;
    #pragma unroll 8
    for (int k = 0; k < F_INS; ++k) acc += hs[r * 136 + k] * w2s[k * C_OUT + c];
    int n = r0 + r;
    if (n <= N_NODES) h2o[(size_t)n * C_OUT + c] = acc;   // dummy row: acc==0

    // fused alpha2: 16-lane butterfly within each row group
    float sa = acc * a2s[c];
    float sd = acc * a2d[c];
    #pragma unroll
    for (int m = 1; m < 16; m <<= 1) {
        sa += __shfl_xor(sa, m);
        sd += __shfl_xor(sd, m);
    }
    if (c == 0 && n <= N_NODES) {
        as2o[n] = (n == N_NODES) ? -1e30f : sa;           // dummy: w=0
        ad2o[n] = sd;
    }
}

// ---- k_gat2 pipeline macros (parameterized by stream) ----
#define G2_ISSUE(I, H2C, ASC, v0,v1,v2,v3,v4,v5,v6,v7, A) do { \
    u32 ix_=(I).x, iy_=(I).y, iz_=(I).z, iw_=(I).w; \
    v0 = *(const float*)((H2C) + (((ix_ & 0xFFFFu) << 6) | c4)); \
    v1 = *(const float*)((H2C) + (((ix_ >> 16)     << 6) | c4)); \
    v2 = *(const float*)((H2C) + (((iy_ & 0xFFFFu) << 6) | c4)); \
    v3 = *(const float*)((H2C) + (((iy_ >> 16)     << 6) | c4)); \
    v4 = *(const float*)((H2C) + (((iz_ & 0xFFFFu) << 6) | c4)); \
    v5 = *(const float*)((H2C) + (((iz_ >> 16)     << 6) | c4)); \
    v6 = *(const float*)((H2C) + (((iw_ & 0xFFFFu) << 6) | c4)); \
    v7 = *(const float*)((H2C) + (((iw_ >> 16)     << 6) | c4)); \
    u32 ds_ = (jsel & 4) ? ((jsel & 2) ? iw_ : iz_) : ((jsel & 2) ? iy_ : ix_); \
    u32 sA_ = (jsel & 1) ? (ds_ >> 16) : (ds_ & 0xFFFFu); \
    A = *(const float*)((ASC) + (sA_ << 2)); \
} while (0)

#define G2_CONS(v0,v1,v2,v3,v4,v5,v6,v7, A, AD, DEN, ACC) do { \
    int wli_ = __float_as_int(__expf(lrelu((A) + (AD)))); \
    float w0 = __int_as_float(__builtin_amdgcn_ds_bpermute(gb,      wli_)); \
    float w1 = __int_as_float(__builtin_amdgcn_ds_bpermute(gb + 4,  wli_)); \
    float w2 = __int_as_float(__builtin_amdgcn_ds_bpermute(gb + 8,  wli_)); \
    float w3 = __int_as_float(__builtin_amdgcn_ds_bpermute(gb + 12, wli_)); \
    float w4 = __int_as_float(__builtin_amdgcn_ds_bpermute(gb + 16, wli_)); \
    float w5 = __int_as_float(__builtin_amdgcn_ds_bpermute(gb + 20, wli_)); \
    float w6 = __int_as_float(__builtin_amdgcn_ds_bpermute(gb + 24, wli_)); \
    float w7 = __int_as_float(__builtin_amdgcn_ds_bpermute(gb + 28, wli_)); \
    DEN += ((w0 + w1) + (w2 + w3)) + ((w4 + w5) + (w6 + w7)); \
    ACC += (w0 * v0 + w1 * v1 + w2 * v2 + w3 * v3) \
         + (w4 * v4 + w5 * v5 + w6 * v6 + w7 * v7); \
} while (0)

// ---------------- GAT layer 2 both graphs + fused epilogue ----------------
__launch_bounds__(256)
__global__ void k_gat2e(const float* __restrict__ h2, const float* __restrict__ as2,
                        const float* __restrict__ ad2, const int* __restrict__ cursor,
                        const u16* __restrict__ col, const float* __restrict__ b2,
                        float* __restrict__ out) {
    int t = threadIdx.x;
    int node = blockIdx.x * 16 + (t >> 4);   // grid exact: 3125*16 == N_NODES
    int c = t & 15;
    int lane = t & 63;
    u32 c4 = (u32)c << 2;
    int jsel = lane & 7;
    u32 gb = (u32)(lane & 48) << 2;          // bpermute group base byte
    float b2c = b2[c];

    const char* h2Y = (const char*)h2;
    const char* h2Z = (const char*)(h2 + H2_ST);
    const char* asY = (const char*)as2;
    const char* asZ = (const char*)(as2 + AS2_ST);
    const u16* cpY = col + (size_t)node * SLOT;
    const u16* cpZ = col + ((size_t)N_NODES + node) * SLOT;
    float adY = ad2[node];
    float adZ = ad2[AS2_ST + node];

    // self loops
    float wY = __expf(lrelu(*(const float*)(asY + ((u32)node << 2)) + adY));
    float dY = wY;
    float aY = wY * *(const float*)(h2Y + (((u32)node << 6) | c4));
    float wZ = __expf(lrelu(*(const float*)(asZ + ((u32)node << 2)) + adZ));
    float dZ = wZ;
    float aZ = wZ * *(const float*)(h2Z + (((u32)node << 6) | c4));

    int nbY = (min(cursor[node], SLOT) + 7) >> 3;
    int nbZ = (min(cursor[N_NODES + node], SLOT) + 7) >> 3;

    float y0,y1,y2,y3,y4,y5,y6,y7, Ay;
    float z0,z1,z2,z3,z4,z5,z6,z7, Az;
    uint4 I;
    if (nbY) { I = *(const uint4*)cpY; G2_ISSUE(I, h2Y, asY, y0,y1,y2,y3,y4,y5,y6,y7, Ay); }
    if (nbZ) { I = *(const uint4*)cpZ; G2_ISSUE(I, h2Z, asZ, z0,z1,z2,z3,z4,z5,z6,z7, Az); }
    int bY = 0, bZ = 0;
    while (bY < nbY || bZ < nbZ) {
        if (bY < nbY) {
            G2_CONS(y0,y1,y2,y3,y4,y5,y6,y7, Ay, adY, dY, aY);
            ++bY;
            if (bY < nbY) {
                I = *(const uint4*)(cpY + bY * 8);
                G2_ISSUE(I, h2Y, asY, y0,y1,y2,y3,y4,y5,y6,y7, Ay);
            }
        }
        if (bZ < nbZ) {
            G2_CONS(z0,z1,z2,z3,z4,z5,z6,z7, Az, adZ, dZ, aZ);
            ++bZ;
            if (bZ < nbZ) {
                I = *(const uint4*)(cpZ + bZ * 8);
                G2_ISSUE(I, h2Z, asZ, z0,z1,z2,z3,z4,z5,z6,z7, Az);
            }
        }
    }
    float yv = aY / (dY + 1e-16f) + b2c;
    float zv = aZ / (dZ + 1e-16f) + b2c;

    float my = yv, mz = zv;
    #pragma unroll
    for (int m = 1; m < 16; m <<= 1) {
        my = fmaxf(my, __shfl_xor(my, m));
        mz = fmaxf(mz, __shfl_xor(mz, m));
    }
    float sy = __expf(yv - my), sz = __expf(zv - mz);
    float dot = yv * zv, ny = yv * yv, nz = zv * zv;
    #pragma unroll
    for (int m = 1; m < 16; m <<= 1) {
        sy  += __shfl_xor(sy, m);
        sz  += __shfl_xor(sz, m);
        dot += __shfl_xor(dot, m);
        ny  += __shfl_xor(ny, m);
        nz  += __shfl_xor(nz, m);
    }
    float lsey = my + __logf(sy);
    float lsez = mz + __logf(sz);
    float omc = 1.f - dot / (fmaxf(sqrtf(ny), 1e-8f) * fmaxf(sqrtf(nz), 1e-8f));

    const int O1 = N_NODES * C_OUT;            //  800000: 1-cos
    const int O2 = O1 + N_NODES;               //  850000: ls_z
    const int O3 = O2 + N_NODES * C_OUT;       // 1650000: ls_y
    const int O4 = O3 + N_NODES * C_OUT;       // 2450000: ls_y
    float ly = yv - lsey;
    float lz = zv - lsez;
    int base = node * 16 + c;
    out[base]      = ly;
    out[O2 + base] = lz;
    out[O3 + base] = ly;
    out[O4 + base] = ly;
    if (c == 0) out[O1 + node] = omc;
}

extern "C" void kernel_launch(void* const* d_in, const int* in_sizes, int n_in,
                              void* d_out, int out_size, void* d_ws, size_t ws_size,
                              hipStream_t stream) {
    (void)in_sizes; (void)n_in; (void)out_size; (void)ws_size;
    const float* x1  = (const float*)d_in[0];
    const int*   ei1 = (const int*)d_in[1];
    const float* x2  = (const float*)d_in[2];
    const int*   ei2 = (const int*)d_in[3];
    const float* W1  = (const float*)d_in[4];
    const float* a1s = (const float*)d_in[5];
    const float* a1d = (const float*)d_in[6];
    const float* b1  = (const float*)d_in[7];
    const float* W2  = (const float*)d_in[8];
    const float* a2s = (const float*)d_in[9];
    const float* a2d = (const float*)d_in[10];
    const float* b2  = (const float*)d_in[11];
    float* out = (float*)d_out;

    // Workspace layout: ~78 MB. bucket (8 MB) aliases hL1 (25.6 MB): bucket is
    // consumed by k_build (L3) before k_gat1 (L4) first writes hL1.
    char* p = (char*)d_ws;
    int* gcur      = (int*)p; p += (size_t)2 * NCLS * GPAD * 4;      //  16 KB (line-padded)
    u32* w1t       = (u32*)p; p += (size_t)128 * 64 * 4;             //  32 KB (bf16 W1T [c][k])
    u32* a1t       = (u32*)p; p += (size_t)16 * 64 * 4;              //   4 KB (bf16 A1T [n][k])
    int* cursor    = (int*)p; p += (size_t)2 * N_NODES * 4;          //   0.4 MB
    u16* col       = (u16*)p; p += (size_t)2 * N_NODES * SLOT * 2;   //  12.8 MB
    float* as1  = (float*)p; p += (size_t)2 * AS_ST * 4;             //   3.2 MB
    float* ad1  = (float*)p; p += (size_t)2 * AS_ST * 4;             //   3.2 MB
    float* h2   = (float*)p; p += (size_t)2 * H2_ST * 4;             //   6.4 MB
    float* as2  = (float*)p; p += (size_t)2 * AS2_ST * 4;            //   0.4 MB
    float* ad2  = (float*)p; p += (size_t)2 * AS2_ST * 4;            //   0.4 MB
    u32* hL1    = (u32*)p;   p += (size_t)2 * HL1_ST * 4;            //  25.6 MB (bf16)
    u32* h1b    = (u32*)p;   p += (size_t)2 * H1B_ST * 4;            //  25.6 MB (bf16)
    u32* bucket = hL1;                                               //   8 MB alias

    k_wt    <<<33, 256, 0, stream>>>(W1, a1s, a1d, w1t, a1t, gcur);
    k_bg1   <<<2 * NB_BKT + 2 * NB_G1, 256, 0, stream>>>(ei1, ei2, gcur, bucket,
                                                         x1, x2, w1t, a1t, h1b, as1, ad1);
    k_build <<<2 * NCLS, 1024, 0, stream>>>(gcur, bucket, cursor, col);
    k_gat1  <<<2 * NB_GAT1, 256, 0, stream>>>(h1b, as1, ad1, cursor, col, b1, hL1);
    k_gemm2 <<<2 * NB_G2, 256, 0, stream>>>(hL1, W2, a2s, a2d, h2, as2, ad2);
    k_gat2e <<<N_NODES / 16, 256, 0, stream>>>(h2, as2, ad2, cursor, col, b2, out);
}